// Round 2
// baseline (1432.530 us; speedup 1.0000x reference)
//
#include <hip/hip_runtime.h>

typedef unsigned short u16;
typedef unsigned int u32;
typedef float f32x4 __attribute__((ext_vector_type(4)));
typedef __bf16 bf16x8 __attribute__((ext_vector_type(8)));

// ---------- helpers ----------
__device__ __forceinline__ u16 f2bf(float f){
  u32 u = __builtin_bit_cast(u32, f);
  u32 r = (u + 0x7fffu + ((u >> 16) & 1u)) >> 16;
  return (u16)r;
}
__device__ __forceinline__ float bf2f(u16 h){
  return __builtin_bit_cast(float, ((u32)h) << 16);
}
__device__ __forceinline__ void gl_lds16(const void* g, void* l){
  __builtin_amdgcn_global_load_lds((__attribute__((address_space(1))) void*)g,
                                   (__attribute__((address_space(3))) void*)l,
                                   16, 0, 0);
}
__device__ __forceinline__ float sigf(float x){ return 1.f/(1.f + __expf(-x)); }

// ---------- sums ----------
__global__ __launch_bounds__(256) void k_rowsum(const float* __restrict__ adj, float* __restrict__ inv_rs){
  int j = blockIdx.x; int tid = threadIdx.x;
  float s = 0.f;
  for (int i = tid; i < 2048; i += 256) s += adj[(long)j*2048 + i];
  for (int off = 32; off; off >>= 1) s += __shfl_down(s, off, 64);
  __shared__ float red[4];
  if ((tid & 63) == 0) red[tid >> 6] = s;
  __syncthreads();
  if (tid == 0){
    float t = red[0] + red[1] + red[2] + red[3];
    inv_rs[j] = 1.f / fmaxf(t, 1e-8f);
  }
}

__global__ __launch_bounds__(256) void k_colsum(const float* __restrict__ adj, float* __restrict__ inv_cs){
  __shared__ float red[4*64];
  int j0 = blockIdx.x * 64;
  int t = threadIdx.x; int jj = t & 63; int w = t >> 6;
  float s = 0.f;
  for (int i = w; i < 2048; i += 4) s += adj[(long)i*2048 + j0 + jj];
  red[w*64 + jj] = s;
  __syncthreads();
  if (t < 64){
    float tot = red[t] + red[64+t] + red[128+t] + red[192+t];
    inv_cs[j0 + t] = 1.f / fmaxf(tot, 1e-8f);
  }
}

// S0[i][j] = adj[j][i] * inv_rs[j]  (LDS-tiled transpose)
__global__ __launch_bounds__(256) void k_build_S0(const float* __restrict__ adj, const float* __restrict__ inv_rs, u16* __restrict__ S0){
  __shared__ u16 t[64*66];
  int i0 = blockIdx.x * 64, j0 = blockIdx.y * 64;
  int tid = threadIdx.x;
  for (int e = tid; e < 4096; e += 256){
    int jj = e >> 6, ii = e & 63;
    t[jj*66 + ii] = f2bf(adj[(long)(j0+jj)*2048 + i0 + ii] * inv_rs[j0+jj]);
  }
  __syncthreads();
  for (int e = tid; e < 4096; e += 256){
    int ii = e >> 6, jj = e & 63;
    S0[(long)(i0+ii)*2048 + j0 + jj] = t[jj*66 + ii];
  }
}

// S1[i][j] = adj[i][j] * inv_cs[j]
__global__ __launch_bounds__(256) void k_build_S1(const float* __restrict__ adj, const float* __restrict__ inv_cs, u16* __restrict__ S1){
  long idx = ((long)blockIdx.x*256 + threadIdx.x) * 4;
  int j = (int)(idx & 2047);
  float4 a = *(const float4*)(adj + idx);
  float4 c = *(const float4*)(inv_cs + j);
  ushort4 o;
  o.x = f2bf(a.x * c.x); o.y = f2bf(a.y * c.y);
  o.z = f2bf(a.z * c.z); o.w = f2bf(a.w * c.w);
  *(ushort4*)(S1 + idx) = o;
}

// WT[o][k] = w[(f*5+m)*OUTr + o] for k=(m,f), zero-padded.  WT is 128 x Kd.
__global__ __launch_bounds__(256) void k_packW(const float* __restrict__ w, u16* __restrict__ WT,
                                               int OUTr, int F, int Fp, int Kd){
  int idx = blockIdx.x*256 + threadIdx.x;
  if (idx >= 128*Kd) return;
  int o = idx / Kd, k = idx - o*Kd;
  int m = k / Fp, f = k - m*Fp;
  float v = 0.f;
  if (o < OUTr && m < 5 && f < F) v = w[(long)(f*5 + m)*OUTr + o];
  WT[idx] = f2bf(v);
}

// hidden transpose into X0T rows (b, rowoff+u) and D cols (coloff+u); layer-0 extras: inp row/col + pads
__global__ __launch_bounds__(256) void k_hx_build(const float* __restrict__ hx, const float* __restrict__ inp,
                                                  u16* __restrict__ X0T, u16* __restrict__ D,
                                                  int Fp, int rowoff, long ldD, int coloff, int l0extras){
  __shared__ u16 t[64*66];
  int b = blockIdx.x, n0 = blockIdx.y * 64;
  int tid = threadIdx.x;
  const float* hb = hx + (long)b*2048*64;
  for (int e = tid; e < 4096; e += 256){
    int ni = e >> 6, u = e & 63;
    t[ni*66 + u] = f2bf(hb[(long)(n0+ni)*64 + u]);
  }
  __syncthreads();
  for (int e = tid; e < 4096; e += 256){
    int u = e >> 6, ni = e & 63;
    X0T[((long)b*Fp + rowoff + u)*2048 + n0 + ni] = t[ni*66 + u];
  }
  for (int e = tid; e < 4096; e += 256){
    int ni = e >> 6, u = e & 63;
    D[((long)(b*2048 + n0 + ni))*ldD + coloff + u] = t[ni*66 + u];
  }
  if (l0extras){
    if (tid < 64){
      u16 v = f2bf(inp[(long)b*2048 + n0 + tid]);
      X0T[((long)b*Fp)*2048 + n0 + tid] = v;
      D[((long)(b*2048 + n0 + tid))*ldD] = v;
    }
    for (int e = tid; e < 7*64; e += 256){
      int f = 65 + (e >> 6), ni = e & 63;
      X0T[((long)b*Fp + f)*2048 + n0 + ni] = 0;
    }
    for (int e = tid; e < 64*31; e += 256){
      int ni = e / 31, wc = e - ni*31;
      int col = (wc < 7) ? (65 + wc) : (353 + wc);   // {65..71, 360..383}
      D[((long)(b*2048 + n0 + ni))*ldD + col] = 0;
    }
  }
}

// pack 4 diffusion outputs (XT layout, C x 2048) into D slices m=1..4
__global__ __launch_bounds__(256) void k_pack(const u16* __restrict__ T1a, const u16* __restrict__ T2a,
                                              const u16* __restrict__ T1b, const u16* __restrict__ T2b,
                                              u16* __restrict__ D, int Fp, long ldD){
  const u16* src = (blockIdx.z == 0) ? T1a : (blockIdx.z == 1) ? T2a : (blockIdx.z == 2) ? T1b : T2b;
  int mbase = (blockIdx.z + 1) * Fp;
  int c0 = blockIdx.x * 64, n0 = blockIdx.y * 64;
  __shared__ u16 t[64*66];
  int tid = threadIdx.x;
  for (int e = tid; e < 4096; e += 256){
    int ci = e >> 6, ni = e & 63;
    t[ci*66 + ni] = src[(long)(c0+ci)*2048 + n0 + ni];
  }
  __syncthreads();
  for (int e = tid; e < 4096; e += 256){
    int ni = e >> 6, cj = e & 63;
    int c = c0 + cj;
    int bb = c / Fp, f = c - bb*Fp;
    D[((long)(bb*2048 + n0 + ni))*ldD + mbase + f] = t[cj*66 + ni];
  }
}

// ---------- the GEMM ----------
// Out[i,c] = op( sum_k A[i,k]*Bt[c,k] )
// MODE 0: OutT[c,i] = bf16(acc)                  (u16 OutT, ld=ldOut)
// MODE 1: OutT[c,i] = bf16(2*acc - Aux[c,i])     (x2 chebyshev step)
// MODE 2: OutT[c,i] = acc (f32)
template<int MODE>
__global__ __launch_bounds__(256) void gemm_bt(const u16* __restrict__ A, const u16* __restrict__ Bt,
                                               void* __restrict__ Out, const u16* __restrict__ Aux,
                                               int K, long ldOut){
  __shared__ u16 lA[4096];   // 128 x 32 bf16, chunk-swizzled
  __shared__ u16 lB[4096];
  int tid = threadIdx.x;
  int wv = tid >> 6, lane = tid & 63;
  int q = lane >> 4, r16 = lane & 15;
  long tM = (long)blockIdx.x * 128;
  long tC = (long)blockIdx.y * 128;

  // staging: linear 16B chunk L holds row r=L>>2, global chunk c=(L&3)^(r&3)
  int L0 = wv*64 + lane, L1 = 256 + wv*64 + lane;
  int r0 = L0 >> 2, c0s = (L0 & 3) ^ (r0 & 3);
  int r1 = L1 >> 2, c1s = (L1 & 3) ^ (r1 & 3);
  const u16* a0 = A + (tM + r0)*(long)K + c0s*8;
  const u16* a1 = A + (tM + r1)*(long)K + c1s*8;
  const u16* b0 = Bt + (tC + r0)*(long)K + c0s*8;
  const u16* b1 = Bt + (tC + r1)*(long)K + c1s*8;
  u16* lA0 = lA + wv*512;  u16* lA1 = lA + 2048 + wv*512;
  u16* lB0 = lB + wv*512;  u16* lB1 = lB + 2048 + wv*512;

  f32x4 acc[4][4];
  #pragma unroll
  for (int i = 0; i < 4; i++)
    #pragma unroll
    for (int j = 0; j < 4; j++){ acc[i][j][0]=0.f; acc[i][j][1]=0.f; acc[i][j][2]=0.f; acc[i][j][3]=0.f; }

  int wm = wv & 1, wn = wv >> 1;
  int aoff[4], boff[4];
  #pragma unroll
  for (int s = 0; s < 4; s++){
    int m = wm*64 + s*16 + r16;
    aoff[s] = (m*4 + (q ^ (m & 3))) * 8;
    int n = wn*64 + s*16 + r16;
    boff[s] = (n*4 + (q ^ (n & 3))) * 8;
  }

  for (int k0 = 0; k0 < K; k0 += 32){
    __syncthreads();
    gl_lds16(a0 + k0, lA0);
    gl_lds16(a1 + k0, lA1);
    gl_lds16(b0 + k0, lB0);
    gl_lds16(b1 + k0, lB1);
    asm volatile("s_waitcnt vmcnt(0)" ::: "memory");
    __syncthreads();
    bf16x8 af[4], bfr[4];
    #pragma unroll
    for (int s = 0; s < 4; s++){
      af[s]  = *(const bf16x8*)&lA[aoff[s]];
      bfr[s] = *(const bf16x8*)&lB[boff[s]];
    }
    #pragma unroll
    for (int i = 0; i < 4; i++)
      #pragma unroll
      for (int j = 0; j < 4; j++)
        acc[i][j] = __builtin_amdgcn_mfma_f32_16x16x32_bf16(af[i], bfr[j], acc[i][j], 0, 0, 0);
  }

  // epilogue: C/D layout col=lane&15, row=quad*4+reg  -> transposed writes are contiguous
  #pragma unroll
  for (int i = 0; i < 4; i++){
    long gi = tM + wm*64 + i*16 + q*4;
    #pragma unroll
    for (int j = 0; j < 4; j++){
      long gc = tC + wn*64 + j*16 + r16;
      f32x4 v = acc[i][j];
      if (MODE == 2){
        *(f32x4*)((float*)Out + gc*ldOut + gi) = v;
      } else {
        if (MODE == 1){
          ushort4 x0 = *(const ushort4*)(Aux + gc*ldOut + gi);
          v[0] = 2.f*v[0] - bf2f(x0.x);
          v[1] = 2.f*v[1] - bf2f(x0.y);
          v[2] = 2.f*v[2] - bf2f(x0.z);
          v[3] = 2.f*v[3] - bf2f(x0.w);
        }
        ushort4 o;
        o.x = f2bf(v[0]); o.y = f2bf(v[1]); o.z = f2bf(v[2]); o.w = f2bf(v[3]);
        *(ushort4*)((u16*)Out + gc*ldOut + gi) = o;
      }
    }
  }
}

// ---------- GRU epilogues ----------
// r = sigmoid(GT[u] + bg[u]); X0T row (b,rowoff+u) := r*hx (in place); D col (coloff+u) := same
__global__ __launch_bounds__(256) void k_gate_ep(const float* __restrict__ GT, const float* __restrict__ bg,
                                                 u16* __restrict__ X0T, u16* __restrict__ D,
                                                 int Fp, int rowoff, long ldD, int coloff){
  __shared__ u16 t[64*66];
  int b = blockIdx.x, n0 = blockIdx.y * 64;
  int tid = threadIdx.x;
  long bn0 = (long)b*2048 + n0;
  for (int e = tid; e < 4096; e += 256){
    int u = e >> 6, ni = e & 63;
    float r = sigf(GT[(long)u*65536 + bn0 + ni] + bg[u]);
    long xo = ((long)b*Fp + rowoff + u)*2048 + n0 + ni;
    float hxv = bf2f(X0T[xo]);
    u16 p = f2bf(r * hxv);
    X0T[xo] = p;
    t[ni*66 + u] = p;
  }
  __syncthreads();
  for (int e = tid; e < 4096; e += 256){
    int ni = e >> 6, u = e & 63;
    D[(bn0 + ni)*ldD + coloff + u] = t[ni*66 + u];
  }
}

// c = tanh(CT[u]+bc[u]); ugate = sigmoid(GT[64+u]+bg[64+u]); h = u*hx+(1-u)*c
// writes hout (f32), optionally next-layer X0T rows (b,u) + D m0 cols u, optionally projection out
__global__ __launch_bounds__(256) void k_cand_ep(const float* __restrict__ CT, const float* __restrict__ GT,
                                                 const float* __restrict__ bc, const float* __restrict__ bg,
                                                 const float* __restrict__ hx, float* __restrict__ hout,
                                                 u16* __restrict__ X0T_next, u16* __restrict__ Dnext,
                                                 const float* __restrict__ wproj, const float* __restrict__ bproj,
                                                 float* __restrict__ out){
  __shared__ u16 tc[64*66];
  __shared__ u16 tu[64*66];
  __shared__ u16 th[64*66];
  int b = blockIdx.x, n0 = blockIdx.y * 64;
  int tid = threadIdx.x;
  long bn0 = (long)b*2048 + n0;
  for (int e = tid; e < 4096; e += 256){
    int u = e >> 6, ni = e & 63;
    float cv = tanhf(CT[(long)u*65536 + bn0 + ni] + bc[u]);
    float uv = sigf(GT[(long)(64+u)*65536 + bn0 + ni] + bg[64+u]);
    tc[ni*66 + u] = f2bf(cv);
    tu[ni*66 + u] = f2bf(uv);
  }
  __syncthreads();
  int lane = tid & 63, wv = tid >> 6;
  for (int it = 0; it < 16; ++it){
    int ni = it*4 + wv, u = lane;
    float hxv = hx[((long)b*2048 + n0 + ni)*64 + u];
    float uv = bf2f(tu[ni*66 + u]), cv = bf2f(tc[ni*66 + u]);
    float h = uv*hxv + (1.f - uv)*cv;
    hout[((long)b*2048 + n0 + ni)*64 + u] = h;
    if (Dnext) Dnext[((long)(b*2048 + n0 + ni))*640 + u] = f2bf(h);
    th[ni*66 + u] = f2bf(h);
    if (wproj){
      float v = h * wproj[u];
      for (int off = 32; off; off >>= 1) v += __shfl_down(v, off, 64);
      if (lane == 0) out[(long)b*2048 + n0 + ni] = v + bproj[0];
    }
  }
  __syncthreads();
  if (X0T_next){
    for (int e = tid; e < 4096; e += 256){
      int u = e >> 6, ni = e & 63;
      X0T_next[((long)b*128 + u)*2048 + n0 + ni] = th[ni*66 + u];
    }
  }
}

// ---------- launch ----------
extern "C" void kernel_launch(void* const* d_in, const int* in_sizes, int n_in,
                              void* d_out, int out_size, void* d_ws, size_t ws_size,
                              hipStream_t stream){
  (void)in_sizes; (void)n_in; (void)out_size; (void)ws_size;
  const float* inputs = (const float*)d_in[0];
  const float* hidden = (const float*)d_in[1];
  const float* adj    = (const float*)d_in[2];
  const float* wg0 = (const float*)d_in[3];
  const float* bg0 = (const float*)d_in[4];
  const float* wc0 = (const float*)d_in[5];
  const float* bc0 = (const float*)d_in[6];
  const float* wg1 = (const float*)d_in[7];
  const float* bg1 = (const float*)d_in[8];
  const float* wc1 = (const float*)d_in[9];
  const float* bc1 = (const float*)d_in[10];
  const float* wp  = (const float*)d_in[11];
  const float* bp  = (const float*)d_in[12];
  float* out = (float*)d_out;

  char* p = (char*)d_ws;
  auto alloc = [&](size_t bytes)->char*{ char* r = p; p += (bytes + 255) & ~(size_t)255; return r; };
  float* inv_rs = (float*)alloc(2048*4);
  float* inv_cs = (float*)alloc(2048*4);
  u16* S0  = (u16*)alloc((size_t)2048*2048*2);
  u16* S1  = (u16*)alloc((size_t)2048*2048*2);
  u16* X0a = (u16*)alloc((size_t)2304*2048*2);   // layer0 cat (XT layout)
  u16* X0b = (u16*)alloc((size_t)4096*2048*2);   // layer1 cat
  u16* T1a = (u16*)alloc((size_t)4096*2048*2);
  u16* T2a = (u16*)alloc((size_t)4096*2048*2);
  u16* T1b = (u16*)alloc((size_t)4096*2048*2);
  u16* T2b = (u16*)alloc((size_t)4096*2048*2);
  u16* D   = (u16*)alloc((size_t)65536*640*2);
  float* GT = (float*)alloc((size_t)128*65536*4);
  float* CT = (float*)T1a;                        // alias: CT (32MB) over T1a+T2a, lifetimes disjoint
  u16* WTg0 = (u16*)alloc((size_t)128*384*2);
  u16* WTc0 = (u16*)alloc((size_t)128*384*2);
  u16* WTg1 = (u16*)alloc((size_t)128*640*2);
  u16* WTc1 = (u16*)alloc((size_t)128*640*2);

  const float* hid0 = hidden;
  const float* hid1 = hidden + (size_t)4194304;
  float* h0out = out + 65536;
  float* h1out = out + 65536 + 4194304;

  k_rowsum<<<2048, 256, 0, stream>>>(adj, inv_rs);
  k_colsum<<<32, 256, 0, stream>>>(adj, inv_cs);
  k_build_S0<<<dim3(32,32), 256, 0, stream>>>(adj, inv_rs, S0);
  k_build_S1<<<4096, 256, 0, stream>>>(adj, inv_cs, S1);
  k_packW<<<192, 256, 0, stream>>>(wg0, WTg0, 128, 65, 72, 384);
  k_packW<<<192, 256, 0, stream>>>(wc0, WTc0,  64, 65, 72, 384);
  k_packW<<<320, 256, 0, stream>>>(wg1, WTg1, 128, 128, 128, 640);
  k_packW<<<320, 256, 0, stream>>>(wc1, WTc1,  64, 128, 128, 640);
  k_hx_build<<<dim3(32,32), 256, 0, stream>>>(hid0, inputs, X0a, D, 72, 1, 384, 1, 1);

  dim3 gS0(16, 18), gS1(16, 32), gD(512, 1), gE(32, 32);

  // reference gconv chain (x0 is NOT reset between supports):
  //   xs1 = S0 @ X
  //   xs2 = 2*S0@xs1 - X
  //   xs3 = S1 @ xs1          <-- chained!
  //   xs4 = 2*S1@xs3 - xs1    <-- chained!

  // ---- layer 0 gate ----
  gemm_bt<0><<<gS0, 256, 0, stream>>>(S0, X0a, T1a, nullptr, 2048, 2048);
  gemm_bt<1><<<gS0, 256, 0, stream>>>(S0, T1a, T2a, X0a, 2048, 2048);
  gemm_bt<0><<<gS0, 256, 0, stream>>>(S1, T1a, T1b, nullptr, 2048, 2048);
  gemm_bt<1><<<gS0, 256, 0, stream>>>(S1, T1b, T2b, T1a, 2048, 2048);
  k_pack<<<dim3(36,32,4), 256, 0, stream>>>(T1a, T2a, T1b, T2b, D, 72, 384);
  gemm_bt<2><<<gD, 256, 0, stream>>>(D, WTg0, GT, nullptr, 384, 65536);
  k_gate_ep<<<gE, 256, 0, stream>>>(GT, bg0, X0a, D, 72, 1, 384, 1);

  // ---- layer 0 candidate ----
  gemm_bt<0><<<gS0, 256, 0, stream>>>(S0, X0a, T1a, nullptr, 2048, 2048);
  gemm_bt<1><<<gS0, 256, 0, stream>>>(S0, T1a, T2a, X0a, 2048, 2048);
  gemm_bt<0><<<gS0, 256, 0, stream>>>(S1, T1a, T1b, nullptr, 2048, 2048);
  gemm_bt<1><<<gS0, 256, 0, stream>>>(S1, T1b, T2b, T1a, 2048, 2048);
  k_pack<<<dim3(36,32,4), 256, 0, stream>>>(T1a, T2a, T1b, T2b, D, 72, 384);
  gemm_bt<2><<<gD, 256, 0, stream>>>(D, WTc0, CT, nullptr, 384, 65536);
  k_cand_ep<<<gE, 256, 0, stream>>>(CT, GT, bc0, bg0, hid0, h0out, X0b, D, nullptr, nullptr, nullptr);

  // ---- layer 1 build ----
  k_hx_build<<<dim3(32,32), 256, 0, stream>>>(hid1, nullptr, X0b, D, 128, 64, 640, 64, 0);

  // ---- layer 1 gate ----
  gemm_bt<0><<<gS1, 256, 0, stream>>>(S0, X0b, T1a, nullptr, 2048, 2048);
  gemm_bt<1><<<gS1, 256, 0, stream>>>(S0, T1a, T2a, X0b, 2048, 2048);
  gemm_bt<0><<<gS1, 256, 0, stream>>>(S1, T1a, T1b, nullptr, 2048, 2048);
  gemm_bt<1><<<gS1, 256, 0, stream>>>(S1, T1b, T2b, T1a, 2048, 2048);
  k_pack<<<dim3(64,32,4), 256, 0, stream>>>(T1a, T2a, T1b, T2b, D, 128, 640);
  gemm_bt<2><<<gD, 256, 0, stream>>>(D, WTg1, GT, nullptr, 640, 65536);
  k_gate_ep<<<gE, 256, 0, stream>>>(GT, bg1, X0b, D, 128, 64, 640, 64);

  // ---- layer 1 candidate ----
  gemm_bt<0><<<gS1, 256, 0, stream>>>(S0, X0b, T1a, nullptr, 2048, 2048);
  gemm_bt<1><<<gS1, 256, 0, stream>>>(S0, T1a, T2a, X0b, 2048, 2048);
  gemm_bt<0><<<gS1, 256, 0, stream>>>(S1, T1a, T1b, nullptr, 2048, 2048);
  gemm_bt<1><<<gS1, 256, 0, stream>>>(S1, T1b, T2b, T1a, 2048, 2048);
  k_pack<<<dim3(64,32,4), 256, 0, stream>>>(T1a, T2a, T1b, T2b, D, 128, 640);
  gemm_bt<2><<<gD, 256, 0, stream>>>(D, WTc1, CT, nullptr, 640, 65536);
  k_cand_ep<<<gE, 256, 0, stream>>>(CT, GT, bc1, bg1, hid1, h1out, nullptr, nullptr, wp, bp, out);
}

// Round 3
// 933.597 us; speedup vs baseline: 1.5344x; 1.5344x over previous
//
#include <hip/hip_runtime.h>

typedef unsigned short u16;
typedef unsigned int u32;
typedef float f32x4 __attribute__((ext_vector_type(4)));
typedef __bf16 bf16x8 __attribute__((ext_vector_type(8)));

// ---------- helpers ----------
__device__ __forceinline__ u16 f2bf(float f){
  u32 u = __builtin_bit_cast(u32, f);
  u32 r = (u + 0x7fffu + ((u >> 16) & 1u)) >> 16;
  return (u16)r;
}
__device__ __forceinline__ float bf2f(u16 h){
  return __builtin_bit_cast(float, ((u32)h) << 16);
}
__device__ __forceinline__ void gl_lds16(const void* g, void* l){
  __builtin_amdgcn_global_load_lds((__attribute__((address_space(1))) void*)g,
                                   (__attribute__((address_space(3))) void*)l,
                                   16, 0, 0);
}
__device__ __forceinline__ float sigf(float x){ return 1.f/(1.f + __expf(-x)); }

// ---------- sums ----------
__global__ __launch_bounds__(256) void k_rowsum(const float* __restrict__ adj, float* __restrict__ inv_rs){
  int j = blockIdx.x; int tid = threadIdx.x;
  float s = 0.f;
  for (int i = tid; i < 2048; i += 256) s += adj[(long)j*2048 + i];
  for (int off = 32; off; off >>= 1) s += __shfl_down(s, off, 64);
  __shared__ float red[4];
  if ((tid & 63) == 0) red[tid >> 6] = s;
  __syncthreads();
  if (tid == 0){
    float t = red[0] + red[1] + red[2] + red[3];
    inv_rs[j] = 1.f / fmaxf(t, 1e-8f);
  }
}

__global__ __launch_bounds__(256) void k_zero(float* __restrict__ p){
  p[blockIdx.x*256 + threadIdx.x] = 0.f;
}

// 512 blocks: (32 col-groups x 16 row-groups), each sums a 64x128 tile, atomicAdd per col
__global__ __launch_bounds__(256) void k_colsum2(const float* __restrict__ adj, float* __restrict__ cs){
  int j0 = blockIdx.x * 64, i0 = blockIdx.y * 128;
  int jj = threadIdx.x & 63, w = threadIdx.x >> 6;
  float s = 0.f;
  for (int i = w; i < 128; i += 4) s += adj[(long)(i0+i)*2048 + j0 + jj];
  __shared__ float red[256];
  red[threadIdx.x] = s;
  __syncthreads();
  if (w == 0){
    float t = red[jj] + red[64+jj] + red[128+jj] + red[192+jj];
    atomicAdd(&cs[j0+jj], t);
  }
}

__global__ __launch_bounds__(256) void k_inv(const float* __restrict__ cs, float* __restrict__ inv_cs){
  int i = blockIdx.x*256 + threadIdx.x;
  inv_cs[i] = 1.f / fmaxf(cs[i], 1e-8f);
}

// S0[i][j] = adj[j][i] * inv_rs[j]  (LDS-tiled transpose)
__global__ __launch_bounds__(256) void k_build_S0(const float* __restrict__ adj, const float* __restrict__ inv_rs, u16* __restrict__ S0){
  __shared__ u16 t[64*66];
  int i0 = blockIdx.x * 64, j0 = blockIdx.y * 64;
  int tid = threadIdx.x;
  for (int e = tid; e < 4096; e += 256){
    int jj = e >> 6, ii = e & 63;
    t[jj*66 + ii] = f2bf(adj[(long)(j0+jj)*2048 + i0 + ii] * inv_rs[j0+jj]);
  }
  __syncthreads();
  for (int e = tid; e < 4096; e += 256){
    int ii = e >> 6, jj = e & 63;
    S0[(long)(i0+ii)*2048 + j0 + jj] = t[jj*66 + ii];
  }
}

// S0T[j][i] = adj[j][i] * inv_rs[j]  (row scale, no transpose)
__global__ __launch_bounds__(256) void k_build_S0T(const float* __restrict__ adj, const float* __restrict__ inv_rs, u16* __restrict__ S0T){
  long idx = ((long)blockIdx.x*256 + threadIdx.x) * 4;
  int j = (int)(idx >> 11);
  float s = inv_rs[j];
  float4 a = *(const float4*)(adj + idx);
  ushort4 o;
  o.x = f2bf(a.x * s); o.y = f2bf(a.y * s);
  o.z = f2bf(a.z * s); o.w = f2bf(a.w * s);
  *(ushort4*)(S0T + idx) = o;
}

// S1[i][j] = adj[i][j] * inv_cs[j]
__global__ __launch_bounds__(256) void k_build_S1(const float* __restrict__ adj, const float* __restrict__ inv_cs, u16* __restrict__ S1){
  long idx = ((long)blockIdx.x*256 + threadIdx.x) * 4;
  int j = (int)(idx & 2047);
  float4 a = *(const float4*)(adj + idx);
  float4 c = *(const float4*)(inv_cs + j);
  ushort4 o;
  o.x = f2bf(a.x * c.x); o.y = f2bf(a.y * c.y);
  o.z = f2bf(a.z * c.z); o.w = f2bf(a.w * c.w);
  *(ushort4*)(S1 + idx) = o;
}

// WT[o][k] = w[(f*5+m)*OUTr + o] for k=(m,f), zero-padded.  WT is 128 x Kd.
__global__ __launch_bounds__(256) void k_packW(const float* __restrict__ w, u16* __restrict__ WT,
                                               int OUTr, int F, int Fp, int Kd){
  int idx = blockIdx.x*256 + threadIdx.x;
  if (idx >= 128*Kd) return;
  int o = idx / Kd, k = idx - o*Kd;
  int m = k / Fp, f = k - m*Fp;
  float v = 0.f;
  if (o < OUTr && m < 5 && f < F) v = w[(long)(f*5 + m)*OUTr + o];
  WT[idx] = f2bf(v);
}

// hidden transpose into X0T rows (b, rowoff+u) and D cols (coloff+u); layer-0 extras: inp row/col + pads
__global__ __launch_bounds__(256) void k_hx_build(const float* __restrict__ hx, const float* __restrict__ inp,
                                                  u16* __restrict__ X0T, u16* __restrict__ D,
                                                  int Fp, int rowoff, long ldD, int coloff, int l0extras){
  __shared__ u16 t[64*66];
  int b = blockIdx.x, n0 = blockIdx.y * 64;
  int tid = threadIdx.x;
  const float* hb = hx + (long)b*2048*64;
  for (int e = tid; e < 4096; e += 256){
    int ni = e >> 6, u = e & 63;
    t[ni*66 + u] = f2bf(hb[(long)(n0+ni)*64 + u]);
  }
  __syncthreads();
  for (int e = tid; e < 4096; e += 256){
    int u = e >> 6, ni = e & 63;
    X0T[((long)b*Fp + rowoff + u)*2048 + n0 + ni] = t[ni*66 + u];
  }
  for (int e = tid; e < 4096; e += 256){
    int ni = e >> 6, u = e & 63;
    D[((long)(b*2048 + n0 + ni))*ldD + coloff + u] = t[ni*66 + u];
  }
  if (l0extras){
    if (tid < 64){
      u16 v = f2bf(inp[(long)b*2048 + n0 + tid]);
      X0T[((long)b*Fp)*2048 + n0 + tid] = v;
      D[((long)(b*2048 + n0 + tid))*ldD] = v;
    }
    for (int e = tid; e < 7*64; e += 256){
      int f = 65 + (e >> 6), ni = e & 63;
      X0T[((long)b*Fp + f)*2048 + n0 + ni] = 0;
    }
    for (int e = tid; e < 64*31; e += 256){
      int ni = e / 31, wc = e - ni*31;
      int col = (wc < 7) ? (65 + wc) : (353 + wc);   // {65..71, 360..383}
      D[((long)(b*2048 + n0 + ni))*ldD + col] = 0;
    }
  }
}

// ---------- GEMM core: acc[i][j] += A-tile @ Bt-tile^T over K ----------
__device__ __forceinline__ void gemm_core(const u16* __restrict__ A, const u16* __restrict__ Bt,
                                          int K, long tM, long tC,
                                          u16* lA, u16* lB, f32x4 (&acc)[4][4]){
  int tid = threadIdx.x;
  int wv = tid >> 6, lane = tid & 63;
  int q = lane >> 4, r16 = lane & 15;

  int L0 = wv*64 + lane, L1 = 256 + wv*64 + lane;
  int r0 = L0 >> 2, c0s = (L0 & 3) ^ (r0 & 3);
  int r1 = L1 >> 2, c1s = (L1 & 3) ^ (r1 & 3);
  const u16* a0 = A + (tM + r0)*(long)K + c0s*8;
  const u16* a1 = A + (tM + r1)*(long)K + c1s*8;
  const u16* b0 = Bt + (tC + r0)*(long)K + c0s*8;
  const u16* b1 = Bt + (tC + r1)*(long)K + c1s*8;
  u16* lA0 = lA + wv*512;  u16* lA1 = lA + 2048 + wv*512;
  u16* lB0 = lB + wv*512;  u16* lB1 = lB + 2048 + wv*512;

  #pragma unroll
  for (int i = 0; i < 4; i++)
    #pragma unroll
    for (int j = 0; j < 4; j++){ acc[i][j][0]=0.f; acc[i][j][1]=0.f; acc[i][j][2]=0.f; acc[i][j][3]=0.f; }

  int wm = wv & 1, wn = wv >> 1;
  int aoff[4], boff[4];
  #pragma unroll
  for (int s = 0; s < 4; s++){
    int m = wm*64 + s*16 + r16;
    aoff[s] = (m*4 + (q ^ (m & 3))) * 8;
    int n = wn*64 + s*16 + r16;
    boff[s] = (n*4 + (q ^ (n & 3))) * 8;
  }

  for (int k0 = 0; k0 < K; k0 += 32){
    __syncthreads();
    gl_lds16(a0 + k0, lA0);
    gl_lds16(a1 + k0, lA1);
    gl_lds16(b0 + k0, lB0);
    gl_lds16(b1 + k0, lB1);
    asm volatile("s_waitcnt vmcnt(0)" ::: "memory");
    __syncthreads();
    bf16x8 af[4], bfr[4];
    #pragma unroll
    for (int s = 0; s < 4; s++){
      af[s]  = *(const bf16x8*)&lA[aoff[s]];
      bfr[s] = *(const bf16x8*)&lB[boff[s]];
    }
    #pragma unroll
    for (int i = 0; i < 4; i++)
      #pragma unroll
      for (int j = 0; j < 4; j++)
        acc[i][j] = __builtin_amdgcn_mfma_f32_16x16x32_bf16(af[i], bfr[j], acc[i][j], 0, 0, 0);
  }
}

// ---------- precompute batch 1: z=0: R = S1@S0 (dual write R + RT); z=1: V = 2*S0^2 - I ----------
__global__ __launch_bounds__(256) void gemm_pre(const u16* __restrict__ S0T, const u16* __restrict__ S1,
                                                const u16* __restrict__ S0,
                                                u16* __restrict__ R, u16* __restrict__ RT, u16* __restrict__ V){
  __shared__ u16 lA[4096];
  __shared__ u16 lB[4096];
  f32x4 acc[4][4];
  const u16* Bt = (blockIdx.z == 0) ? S1 : S0;
  long tM = (long)blockIdx.x * 128, tC = (long)blockIdx.y * 128;
  gemm_core(S0T, Bt, 2048, tM, tC, lA, lB, acc);

  int tid = threadIdx.x, wv = tid >> 6, lane = tid & 63;
  int q = lane >> 4, r16 = lane & 15, wm = wv & 1, wn = wv >> 1;
  #pragma unroll
  for (int i = 0; i < 4; i++){
    long gi = tM + wm*64 + i*16 + q*4;
    #pragma unroll
    for (int j = 0; j < 4; j++){
      long gc = tC + wn*64 + j*16 + r16;
      f32x4 v = acc[i][j];
      if (blockIdx.z == 0){
        ushort4 o;
        o.x = f2bf(v[0]); o.y = f2bf(v[1]); o.z = f2bf(v[2]); o.w = f2bf(v[3]);
        *(ushort4*)(R + gc*2048 + gi) = o;
        RT[(gi+0)*2048 + gc] = o.x;
        RT[(gi+1)*2048 + gc] = o.y;
        RT[(gi+2)*2048 + gc] = o.z;
        RT[(gi+3)*2048 + gc] = o.w;
      } else {
        ushort4 o;
        #pragma unroll
        for (int e = 0; e < 4; e++){
          float x = 2.f*v[e] - ((gi+e) == gc ? 1.f : 0.f);
          ((u16*)&o)[e] = f2bf(x);
        }
        *(ushort4*)(V + gc*2048 + gi) = o;
      }
    }
  }
}

// ---------- precompute batch 2: W = 2*S1@R - S0 (A=RT, Bt=S1, aux=S0) ----------
__global__ __launch_bounds__(256) void gemm_w(const u16* __restrict__ RT, const u16* __restrict__ S1,
                                              const u16* __restrict__ S0, u16* __restrict__ W){
  __shared__ u16 lA[4096];
  __shared__ u16 lB[4096];
  f32x4 acc[4][4];
  long tM = (long)blockIdx.x * 128, tC = (long)blockIdx.y * 128;
  gemm_core(RT, S1, 2048, tM, tC, lA, lB, acc);

  int tid = threadIdx.x, wv = tid >> 6, lane = tid & 63;
  int q = lane >> 4, r16 = lane & 15, wm = wv & 1, wn = wv >> 1;
  #pragma unroll
  for (int i = 0; i < 4; i++){
    long gi = tM + wm*64 + i*16 + q*4;
    #pragma unroll
    for (int j = 0; j < 4; j++){
      long gc = tC + wn*64 + j*16 + r16;
      f32x4 v = acc[i][j];
      ushort4 x0 = *(const ushort4*)(S0 + gc*2048 + gi);
      ushort4 o;
      o.x = f2bf(2.f*v[0] - bf2f(x0.x));
      o.y = f2bf(2.f*v[1] - bf2f(x0.y));
      o.z = f2bf(2.f*v[2] - bf2f(x0.z));
      o.w = f2bf(2.f*v[3] - bf2f(x0.w));
      *(ushort4*)(W + gc*2048 + gi) = o;
    }
  }
}

// ---------- batched diffusion: z in {0..3} selects M in {S0,V,R,W}; writes D slice z+1 directly ----------
template<int FP>
__global__ __launch_bounds__(256) void gemm_diff(const u16* __restrict__ M0, const u16* __restrict__ M1,
                                                 const u16* __restrict__ M2, const u16* __restrict__ M3,
                                                 const u16* __restrict__ X, u16* __restrict__ D, long ldD){
  __shared__ u16 lA[4096];
  __shared__ u16 lB[4096];
  f32x4 acc[4][4];
  int z = blockIdx.z;
  const u16* A = (z == 0) ? M0 : (z == 1) ? M1 : (z == 2) ? M2 : M3;
  long tM = (long)blockIdx.x * 128, tC = (long)blockIdx.y * 128;
  gemm_core(A, X, 2048, tM, tC, lA, lB, acc);

  int tid = threadIdx.x, wv = tid >> 6, lane = tid & 63;
  int q = lane >> 4, r16 = lane & 15, wm = wv & 1, wn = wv >> 1;
  int zb = (z + 1) * FP;
  #pragma unroll
  for (int i = 0; i < 4; i++){
    long gi = tM + wm*64 + i*16 + q*4;
    #pragma unroll
    for (int j = 0; j < 4; j++){
      int gc = (int)(tC + wn*64 + j*16 + r16);
      int b = gc / FP, f = gc - b*FP;
      long rb = (long)b*2048 + gi;
      f32x4 v = acc[i][j];
      D[(rb+0)*ldD + zb + f] = f2bf(v[0]);
      D[(rb+1)*ldD + zb + f] = f2bf(v[1]);
      D[(rb+2)*ldD + zb + f] = f2bf(v[2]);
      D[(rb+3)*ldD + zb + f] = f2bf(v[3]);
    }
  }
}

// ---------- dense: OutT[c][i] = sum_k A[i,k]*Bt[c,k]  (f32 out) ----------
__global__ __launch_bounds__(256) void gemm_dense(const u16* __restrict__ A, const u16* __restrict__ Bt,
                                                  float* __restrict__ Out, int K, long ldOut){
  __shared__ u16 lA[4096];
  __shared__ u16 lB[4096];
  f32x4 acc[4][4];
  long tM = (long)blockIdx.x * 128, tC = (long)blockIdx.y * 128;
  gemm_core(A, Bt, K, tM, tC, lA, lB, acc);

  int tid = threadIdx.x, wv = tid >> 6, lane = tid & 63;
  int q = lane >> 4, r16 = lane & 15, wm = wv & 1, wn = wv >> 1;
  #pragma unroll
  for (int i = 0; i < 4; i++){
    long gi = tM + wm*64 + i*16 + q*4;
    #pragma unroll
    for (int j = 0; j < 4; j++){
      long gc = tC + wn*64 + j*16 + r16;
      *(f32x4*)(Out + gc*ldOut + gi) = acc[i][j];
    }
  }
}

// ---------- GRU epilogues ----------
__global__ __launch_bounds__(256) void k_gate_ep(const float* __restrict__ GT, const float* __restrict__ bg,
                                                 u16* __restrict__ X0T, u16* __restrict__ D,
                                                 int Fp, int rowoff, long ldD, int coloff){
  __shared__ u16 t[64*66];
  int b = blockIdx.x, n0 = blockIdx.y * 64;
  int tid = threadIdx.x;
  long bn0 = (long)b*2048 + n0;
  for (int e = tid; e < 4096; e += 256){
    int u = e >> 6, ni = e & 63;
    float r = sigf(GT[(long)u*65536 + bn0 + ni] + bg[u]);
    long xo = ((long)b*Fp + rowoff + u)*2048 + n0 + ni;
    float hxv = bf2f(X0T[xo]);
    u16 p = f2bf(r * hxv);
    X0T[xo] = p;
    t[ni*66 + u] = p;
  }
  __syncthreads();
  for (int e = tid; e < 4096; e += 256){
    int ni = e >> 6, u = e & 63;
    D[(bn0 + ni)*ldD + coloff + u] = t[ni*66 + u];
  }
}

__global__ __launch_bounds__(256) void k_cand_ep(const float* __restrict__ CT, const float* __restrict__ GT,
                                                 const float* __restrict__ bc, const float* __restrict__ bg,
                                                 const float* __restrict__ hx, float* __restrict__ hout,
                                                 u16* __restrict__ X0T_next, u16* __restrict__ Dnext,
                                                 const float* __restrict__ wproj, const float* __restrict__ bproj,
                                                 float* __restrict__ out){
  __shared__ u16 tc[64*66];
  __shared__ u16 tu[64*66];
  __shared__ u16 th[64*66];
  int b = blockIdx.x, n0 = blockIdx.y * 64;
  int tid = threadIdx.x;
  long bn0 = (long)b*2048 + n0;
  for (int e = tid; e < 4096; e += 256){
    int u = e >> 6, ni = e & 63;
    float cv = tanhf(CT[(long)u*65536 + bn0 + ni] + bc[u]);
    float uv = sigf(GT[(long)(64+u)*65536 + bn0 + ni] + bg[64+u]);
    tc[ni*66 + u] = f2bf(cv);
    tu[ni*66 + u] = f2bf(uv);
  }
  __syncthreads();
  int lane = tid & 63, wv = tid >> 6;
  for (int it = 0; it < 16; ++it){
    int ni = it*4 + wv, u = lane;
    float hxv = hx[((long)b*2048 + n0 + ni)*64 + u];
    float uv = bf2f(tu[ni*66 + u]), cv = bf2f(tc[ni*66 + u]);
    float h = uv*hxv + (1.f - uv)*cv;
    hout[((long)b*2048 + n0 + ni)*64 + u] = h;
    if (Dnext) Dnext[((long)(b*2048 + n0 + ni))*640 + u] = f2bf(h);
    th[ni*66 + u] = f2bf(h);
    if (wproj){
      float v = h * wproj[u];
      for (int off = 32; off; off >>= 1) v += __shfl_down(v, off, 64);
      if (lane == 0) out[(long)b*2048 + n0 + ni] = v + bproj[0];
    }
  }
  __syncthreads();
  if (X0T_next){
    for (int e = tid; e < 4096; e += 256){
      int u = e >> 6, ni = e & 63;
      X0T_next[((long)b*128 + u)*2048 + n0 + ni] = th[ni*66 + u];
    }
  }
}

// ---------- launch ----------
extern "C" void kernel_launch(void* const* d_in, const int* in_sizes, int n_in,
                              void* d_out, int out_size, void* d_ws, size_t ws_size,
                              hipStream_t stream){
  (void)in_sizes; (void)n_in; (void)out_size; (void)ws_size;
  const float* inputs = (const float*)d_in[0];
  const float* hidden = (const float*)d_in[1];
  const float* adj    = (const float*)d_in[2];
  const float* wg0 = (const float*)d_in[3];
  const float* bg0 = (const float*)d_in[4];
  const float* wc0 = (const float*)d_in[5];
  const float* bc0 = (const float*)d_in[6];
  const float* wg1 = (const float*)d_in[7];
  const float* bg1 = (const float*)d_in[8];
  const float* wc1 = (const float*)d_in[9];
  const float* bc1 = (const float*)d_in[10];
  const float* wp  = (const float*)d_in[11];
  const float* bp  = (const float*)d_in[12];
  float* out = (float*)d_out;

  char* p = (char*)d_ws;
  auto alloc = [&](size_t bytes)->char*{ char* r = p; p += (bytes + 255) & ~(size_t)255; return r; };
  float* inv_rs = (float*)alloc(2048*4);
  float* inv_cs = (float*)alloc(2048*4);
  float* cs     = (float*)alloc(2048*4);
  const size_t SB = (size_t)2048*2048*2;
  u16* S0  = (u16*)alloc(SB);
  u16* S0T = (u16*)alloc(SB);
  u16* S1  = (u16*)alloc(SB);
  u16* R   = (u16*)alloc(SB);
  u16* RT  = (u16*)alloc(SB);
  u16* V   = (u16*)alloc(SB);
  u16* W   = (u16*)alloc(SB);
  u16* X0a = (u16*)alloc((size_t)2304*2048*2);   // layer0 cat (XT layout, Fp=72)
  u16* X0b = (u16*)alloc((size_t)4096*2048*2);   // layer1 cat (Fp=128)
  u16* D   = (u16*)alloc((size_t)65536*640*2);
  float* GT = (float*)alloc((size_t)128*65536*4);
  float* CT = (float*)alloc((size_t)128*65536*4);
  u16* WTg0 = (u16*)alloc((size_t)128*384*2);
  u16* WTc0 = (u16*)alloc((size_t)128*384*2);
  u16* WTg1 = (u16*)alloc((size_t)128*640*2);
  u16* WTc1 = (u16*)alloc((size_t)128*640*2);

  const float* hid0 = hidden;
  const float* hid1 = hidden + (size_t)4194304;
  float* h0out = out + 65536;
  float* h1out = out + 65536 + 4194304;

  // ---- setup ----
  k_rowsum<<<2048, 256, 0, stream>>>(adj, inv_rs);
  k_zero<<<8, 256, 0, stream>>>(cs);
  k_colsum2<<<dim3(32,16), 256, 0, stream>>>(adj, cs);
  k_inv<<<8, 256, 0, stream>>>(cs, inv_cs);
  k_build_S0 <<<dim3(32,32), 256, 0, stream>>>(adj, inv_rs, S0);
  k_build_S0T<<<4096, 256, 0, stream>>>(adj, inv_rs, S0T);
  k_build_S1 <<<4096, 256, 0, stream>>>(adj, inv_cs, S1);
  k_packW<<<192, 256, 0, stream>>>(wg0, WTg0, 128, 65, 72, 384);
  k_packW<<<192, 256, 0, stream>>>(wc0, WTc0,  64, 65, 72, 384);
  k_packW<<<320, 256, 0, stream>>>(wg1, WTg1, 128, 128, 128, 640);
  k_packW<<<320, 256, 0, stream>>>(wc1, WTc1,  64, 128, 128, 640);
  k_hx_build<<<dim3(32,32), 256, 0, stream>>>(hid0, inputs, X0a, D, 72, 1, 384, 1, 1);

  // ---- precompute diffusion operators: R=S1@S0, V=2*S0^2-I, W=2*S1@R-S0 ----
  gemm_pre<<<dim3(16,16,2), 256, 0, stream>>>(S0T, S1, S0, R, RT, V);
  gemm_w  <<<dim3(16,16),   256, 0, stream>>>(RT, S1, S0, W);

  dim3 gD0(16, 18, 4), gD1(16, 32, 4), gDen(512, 1), gE(32, 32);

  // ---- layer 0 gate ----
  gemm_diff<72><<<gD0, 256, 0, stream>>>(S0, V, R, W, X0a, D, 384);
  gemm_dense<<<gDen, 256, 0, stream>>>(D, WTg0, GT, 384, 65536);
  k_gate_ep<<<gE, 256, 0, stream>>>(GT, bg0, X0a, D, 72, 1, 384, 1);

  // ---- layer 0 candidate ----
  gemm_diff<72><<<gD0, 256, 0, stream>>>(S0, V, R, W, X0a, D, 384);
  gemm_dense<<<gDen, 256, 0, stream>>>(D, WTc0, CT, 384, 65536);
  k_cand_ep<<<gE, 256, 0, stream>>>(CT, GT, bc0, bg0, hid0, h0out, X0b, D, nullptr, nullptr, nullptr);

  // ---- layer 1 build ----
  k_hx_build<<<dim3(32,32), 256, 0, stream>>>(hid1, nullptr, X0b, D, 128, 64, 640, 64, 0);

  // ---- layer 1 gate ----
  gemm_diff<128><<<gD1, 256, 0, stream>>>(S0, V, R, W, X0b, D, 640);
  gemm_dense<<<gDen, 256, 0, stream>>>(D, WTg1, GT, 640, 65536);
  k_gate_ep<<<gE, 256, 0, stream>>>(GT, bg1, X0b, D, 128, 64, 640, 64);

  // ---- layer 1 candidate ----
  gemm_diff<128><<<gD1, 256, 0, stream>>>(S0, V, R, W, X0b, D, 640);
  gemm_dense<<<gDen, 256, 0, stream>>>(D, WTc1, CT, 640, 65536);
  k_cand_ep<<<gE, 256, 0, stream>>>(CT, GT, bc1, bg1, hid1, h1out, nullptr, nullptr, wp, bp, out);
}

// Round 4
// 849.474 us; speedup vs baseline: 1.6864x; 1.0990x over previous
//
#include <hip/hip_runtime.h>

typedef unsigned short u16;
typedef unsigned int u32;
typedef float f32x4 __attribute__((ext_vector_type(4)));
typedef __bf16 bf16x8 __attribute__((ext_vector_type(8)));

// ---------- helpers ----------
__device__ __forceinline__ u16 f2bf(float f){
  u32 u = __builtin_bit_cast(u32, f);
  u32 r = (u + 0x7fffu + ((u >> 16) & 1u)) >> 16;
  return (u16)r;
}
__device__ __forceinline__ float bf2f(u16 h){
  return __builtin_bit_cast(float, ((u32)h) << 16);
}
__device__ __forceinline__ void gl_lds16(const void* g, void* l){
  __builtin_amdgcn_global_load_lds((__attribute__((address_space(1))) void*)g,
                                   (__attribute__((address_space(3))) void*)l,
                                   16, 0, 0);
}
__device__ __forceinline__ float sigf(float x){ return 1.f/(1.f + __expf(-x)); }

// ---------- sums ----------
__global__ __launch_bounds__(256) void k_rowsum(const float* __restrict__ adj, float* __restrict__ inv_rs){
  int j = blockIdx.x; int tid = threadIdx.x;
  float s = 0.f;
  for (int i = tid; i < 2048; i += 256) s += adj[(long)j*2048 + i];
  for (int off = 32; off; off >>= 1) s += __shfl_down(s, off, 64);
  __shared__ float red[4];
  if ((tid & 63) == 0) red[tid >> 6] = s;
  __syncthreads();
  if (tid == 0){
    float t = red[0] + red[1] + red[2] + red[3];
    inv_rs[j] = 1.f / fmaxf(t, 1e-8f);
  }
}

__global__ __launch_bounds__(256) void k_zero(float* __restrict__ p){
  p[blockIdx.x*256 + threadIdx.x] = 0.f;
}

// 512 blocks: (32 col-groups x 16 row-groups), each sums a 64x128 tile, atomicAdd per col
__global__ __launch_bounds__(256) void k_colsum2(const float* __restrict__ adj, float* __restrict__ cs){
  int j0 = blockIdx.x * 64, i0 = blockIdx.y * 128;
  int jj = threadIdx.x & 63, w = threadIdx.x >> 6;
  float s = 0.f;
  for (int i = w; i < 128; i += 4) s += adj[(long)(i0+i)*2048 + j0 + jj];
  __shared__ float red[256];
  red[threadIdx.x] = s;
  __syncthreads();
  if (w == 0){
    float t = red[jj] + red[64+jj] + red[128+jj] + red[192+jj];
    atomicAdd(&cs[j0+jj], t);
  }
}

__global__ __launch_bounds__(256) void k_inv(const float* __restrict__ cs, float* __restrict__ inv_cs){
  int i = blockIdx.x*256 + threadIdx.x;
  inv_cs[i] = 1.f / fmaxf(cs[i], 1e-8f);
}

// S0[i][j] = adj[j][i] * inv_rs[j]  (LDS-tiled transpose)
__global__ __launch_bounds__(256) void k_build_S0(const float* __restrict__ adj, const float* __restrict__ inv_rs, u16* __restrict__ S0){
  __shared__ u16 t[64*66];
  int i0 = blockIdx.x * 64, j0 = blockIdx.y * 64;
  int tid = threadIdx.x;
  for (int e = tid; e < 4096; e += 256){
    int jj = e >> 6, ii = e & 63;
    t[jj*66 + ii] = f2bf(adj[(long)(j0+jj)*2048 + i0 + ii] * inv_rs[j0+jj]);
  }
  __syncthreads();
  for (int e = tid; e < 4096; e += 256){
    int ii = e >> 6, jj = e & 63;
    S0[(long)(i0+ii)*2048 + j0 + jj] = t[jj*66 + ii];
  }
}

// S0T[j][i] = adj[j][i] * inv_rs[j]  (row scale, no transpose)
__global__ __launch_bounds__(256) void k_build_S0T(const float* __restrict__ adj, const float* __restrict__ inv_rs, u16* __restrict__ S0T){
  long idx = ((long)blockIdx.x*256 + threadIdx.x) * 4;
  int j = (int)(idx >> 11);
  float s = inv_rs[j];
  float4 a = *(const float4*)(adj + idx);
  ushort4 o;
  o.x = f2bf(a.x * s); o.y = f2bf(a.y * s);
  o.z = f2bf(a.z * s); o.w = f2bf(a.w * s);
  *(ushort4*)(S0T + idx) = o;
}

// S1[i][j] = adj[i][j] * inv_cs[j]
__global__ __launch_bounds__(256) void k_build_S1(const float* __restrict__ adj, const float* __restrict__ inv_cs, u16* __restrict__ S1){
  long idx = ((long)blockIdx.x*256 + threadIdx.x) * 4;
  int j = (int)(idx & 2047);
  float4 a = *(const float4*)(adj + idx);
  float4 c = *(const float4*)(inv_cs + j);
  ushort4 o;
  o.x = f2bf(a.x * c.x); o.y = f2bf(a.y * c.y);
  o.z = f2bf(a.z * c.z); o.w = f2bf(a.w * c.w);
  *(ushort4*)(S1 + idx) = o;
}

// WT[o][k] = w[(f*5+m)*OUTr + o] for k=(m,f), zero-padded.  WT is 128 x Kd.
__global__ __launch_bounds__(256) void k_packW(const float* __restrict__ w, u16* __restrict__ WT,
                                               int OUTr, int F, int Fp, int Kd){
  int idx = blockIdx.x*256 + threadIdx.x;
  if (idx >= 128*Kd) return;
  int o = idx / Kd, k = idx - o*Kd;
  int m = k / Fp, f = k - m*Fp;
  float v = 0.f;
  if (o < OUTr && m < 5 && f < F) v = w[(long)(f*5 + m)*OUTr + o];
  WT[idx] = f2bf(v);
}

// hidden transpose into X0T rows (b, rowoff+u) and D cols (coloff+u); layer-0 extras: inp row/col + pads
__global__ __launch_bounds__(256) void k_hx_build(const float* __restrict__ hx, const float* __restrict__ inp,
                                                  u16* __restrict__ X0T, u16* __restrict__ D,
                                                  int Fp, int rowoff, long ldD, int coloff, int l0extras){
  __shared__ u16 t[64*66];
  int b = blockIdx.x, n0 = blockIdx.y * 64;
  int tid = threadIdx.x;
  const float* hb = hx + (long)b*2048*64;
  for (int e = tid; e < 4096; e += 256){
    int ni = e >> 6, u = e & 63;
    t[ni*66 + u] = f2bf(hb[(long)(n0+ni)*64 + u]);
  }
  __syncthreads();
  for (int e = tid; e < 4096; e += 256){
    int u = e >> 6, ni = e & 63;
    X0T[((long)b*Fp + rowoff + u)*2048 + n0 + ni] = t[ni*66 + u];
  }
  for (int e = tid; e < 4096; e += 256){
    int ni = e >> 6, u = e & 63;
    D[((long)(b*2048 + n0 + ni))*ldD + coloff + u] = t[ni*66 + u];
  }
  if (l0extras){
    if (tid < 64){
      u16 v = f2bf(inp[(long)b*2048 + n0 + tid]);
      X0T[((long)b*Fp)*2048 + n0 + tid] = v;
      D[((long)(b*2048 + n0 + tid))*ldD] = v;
    }
    for (int e = tid; e < 7*64; e += 256){
      int f = 65 + (e >> 6), ni = e & 63;
      X0T[((long)b*Fp + f)*2048 + n0 + ni] = 0;
    }
    for (int e = tid; e < 64*31; e += 256){
      int ni = e / 31, wc = e - ni*31;
      int col = (wc < 7) ? (65 + wc) : (353 + wc);   // {65..71, 360..383}
      D[((long)(b*2048 + n0 + ni))*ldD + col] = 0;
    }
  }
}

// ---------- GEMM core: acc[i][j] += A-tile @ Bt-tile^T over K ----------
// LDS chunk swizzle: stored chunk = c ^ ((r>>1)&3) -> frag b128 reads cover all
// 8 bank-quads per 8-lane issue group (conflict-free; old (r&3) gave 2-way).
__device__ __forceinline__ void gemm_core(const u16* __restrict__ A, const u16* __restrict__ Bt,
                                          int K, long tM, long tC,
                                          u16* lA, u16* lB, f32x4 (&acc)[4][4]){
  int tid = threadIdx.x;
  int wv = tid >> 6, lane = tid & 63;
  int q = lane >> 4, r16 = lane & 15;

  int L0 = wv*64 + lane, L1 = 256 + wv*64 + lane;
  int r0 = L0 >> 2, c0s = (L0 & 3) ^ ((r0 >> 1) & 3);
  int r1 = L1 >> 2, c1s = (L1 & 3) ^ ((r1 >> 1) & 3);
  const u16* a0 = A + (tM + r0)*(long)K + c0s*8;
  const u16* a1 = A + (tM + r1)*(long)K + c1s*8;
  const u16* b0 = Bt + (tC + r0)*(long)K + c0s*8;
  const u16* b1 = Bt + (tC + r1)*(long)K + c1s*8;
  u16* lA0 = lA + wv*512;  u16* lA1 = lA + 2048 + wv*512;
  u16* lB0 = lB + wv*512;  u16* lB1 = lB + 2048 + wv*512;

  #pragma unroll
  for (int i = 0; i < 4; i++)
    #pragma unroll
    for (int j = 0; j < 4; j++){ acc[i][j][0]=0.f; acc[i][j][1]=0.f; acc[i][j][2]=0.f; acc[i][j][3]=0.f; }

  int wm = wv & 1, wn = wv >> 1;
  int aoff[4], boff[4];
  #pragma unroll
  for (int s = 0; s < 4; s++){
    int m = wm*64 + s*16 + r16;
    aoff[s] = (m*4 + (q ^ ((m >> 1) & 3))) * 8;
    int n = wn*64 + s*16 + r16;
    boff[s] = (n*4 + (q ^ ((n >> 1) & 3))) * 8;
  }

  for (int k0 = 0; k0 < K; k0 += 32){
    __syncthreads();
    gl_lds16(a0 + k0, lA0);
    gl_lds16(a1 + k0, lA1);
    gl_lds16(b0 + k0, lB0);
    gl_lds16(b1 + k0, lB1);
    asm volatile("s_waitcnt vmcnt(0)" ::: "memory");
    __syncthreads();
    bf16x8 af[4], bfr[4];
    #pragma unroll
    for (int s = 0; s < 4; s++){
      af[s]  = *(const bf16x8*)&lA[aoff[s]];
      bfr[s] = *(const bf16x8*)&lB[boff[s]];
    }
    #pragma unroll
    for (int i = 0; i < 4; i++)
      #pragma unroll
      for (int j = 0; j < 4; j++)
        acc[i][j] = __builtin_amdgcn_mfma_f32_16x16x32_bf16(af[i], bfr[j], acc[i][j], 0, 0, 0);
  }
}

// ---------- precompute batch 1: z=0: R = S1@S0 (dual write R + RT); z=1: V = 2*S0^2 - I ----------
__global__ __launch_bounds__(256) void gemm_pre(const u16* __restrict__ S0T, const u16* __restrict__ S1,
                                                const u16* __restrict__ S0,
                                                u16* __restrict__ R, u16* __restrict__ RT, u16* __restrict__ V){
  __shared__ u16 lA[4096];
  __shared__ u16 lB[4096];
  f32x4 acc[4][4];
  const u16* Bt = (blockIdx.z == 0) ? S1 : S0;
  long tM = (long)blockIdx.x * 128, tC = (long)blockIdx.y * 128;
  gemm_core(S0T, Bt, 2048, tM, tC, lA, lB, acc);

  int tid = threadIdx.x, wv = tid >> 6, lane = tid & 63;
  int q = lane >> 4, r16 = lane & 15, wm = wv & 1, wn = wv >> 1;
  #pragma unroll
  for (int i = 0; i < 4; i++){
    long gi = tM + wm*64 + i*16 + q*4;
    #pragma unroll
    for (int j = 0; j < 4; j++){
      long gc = tC + wn*64 + j*16 + r16;
      f32x4 v = acc[i][j];
      if (blockIdx.z == 0){
        ushort4 o;
        o.x = f2bf(v[0]); o.y = f2bf(v[1]); o.z = f2bf(v[2]); o.w = f2bf(v[3]);
        *(ushort4*)(R + gc*2048 + gi) = o;
        RT[(gi+0)*2048 + gc] = o.x;
        RT[(gi+1)*2048 + gc] = o.y;
        RT[(gi+2)*2048 + gc] = o.z;
        RT[(gi+3)*2048 + gc] = o.w;
      } else {
        ushort4 o;
        #pragma unroll
        for (int e = 0; e < 4; e++){
          float x = 2.f*v[e] - ((gi+e) == gc ? 1.f : 0.f);
          ((u16*)&o)[e] = f2bf(x);
        }
        *(ushort4*)(V + gc*2048 + gi) = o;
      }
    }
  }
}

// ---------- precompute batch 2: W = 2*S1@R - S0 (A=RT, Bt=S1, aux=S0) ----------
__global__ __launch_bounds__(256) void gemm_w(const u16* __restrict__ RT, const u16* __restrict__ S1,
                                              const u16* __restrict__ S0, u16* __restrict__ W){
  __shared__ u16 lA[4096];
  __shared__ u16 lB[4096];
  f32x4 acc[4][4];
  long tM = (long)blockIdx.x * 128, tC = (long)blockIdx.y * 128;
  gemm_core(RT, S1, 2048, tM, tC, lA, lB, acc);

  int tid = threadIdx.x, wv = tid >> 6, lane = tid & 63;
  int q = lane >> 4, r16 = lane & 15, wm = wv & 1, wn = wv >> 1;
  #pragma unroll
  for (int i = 0; i < 4; i++){
    long gi = tM + wm*64 + i*16 + q*4;
    #pragma unroll
    for (int j = 0; j < 4; j++){
      long gc = tC + wn*64 + j*16 + r16;
      f32x4 v = acc[i][j];
      ushort4 x0 = *(const ushort4*)(S0 + gc*2048 + gi);
      ushort4 o;
      o.x = f2bf(2.f*v[0] - bf2f(x0.x));
      o.y = f2bf(2.f*v[1] - bf2f(x0.y));
      o.z = f2bf(2.f*v[2] - bf2f(x0.z));
      o.w = f2bf(2.f*v[3] - bf2f(x0.w));
      *(ushort4*)(W + gc*2048 + gi) = o;
    }
  }
}

// ---------- batched diffusion (gate: full cat X): z in {0..3} selects M in {S0,V,R,W}; writes D slice z+1 ----------
template<int FP>
__global__ __launch_bounds__(256) void gemm_diff(const u16* __restrict__ M0, const u16* __restrict__ M1,
                                                 const u16* __restrict__ M2, const u16* __restrict__ M3,
                                                 const u16* __restrict__ X, u16* __restrict__ D, long ldD){
  __shared__ u16 lA[4096];
  __shared__ u16 lB[4096];
  f32x4 acc[4][4];
  int z = blockIdx.z;
  const u16* A = (z == 0) ? M0 : (z == 1) ? M1 : (z == 2) ? M2 : M3;
  long tM = (long)blockIdx.x * 128, tC = (long)blockIdx.y * 128;
  gemm_core(A, X, 2048, tM, tC, lA, lB, acc);

  int tid = threadIdx.x, wv = tid >> 6, lane = tid & 63;
  int q = lane >> 4, r16 = lane & 15, wm = wv & 1, wn = wv >> 1;
  int zb = (z + 1) * FP;
  #pragma unroll
  for (int i = 0; i < 4; i++){
    long gi = tM + wm*64 + i*16 + q*4;
    #pragma unroll
    for (int j = 0; j < 4; j++){
      int gc = (int)(tC + wn*64 + j*16 + r16);
      int b = gc / FP, f = gc - b*FP;
      long rb = (long)b*2048 + gi;
      f32x4 v = acc[i][j];
      D[(rb+0)*ldD + zb + f] = f2bf(v[0]);
      D[(rb+1)*ldD + zb + f] = f2bf(v[1]);
      D[(rb+2)*ldD + zb + f] = f2bf(v[2]);
      D[(rb+3)*ldD + zb + f] = f2bf(v[3]);
    }
  }
}

// ---------- candidate diffusion: only the r*hx block (Xr: 2048 x 2048, rows = b*64+u) ----------
// writes D col (z+1)*Fp + Fin + u   (inp-part cols already hold gate-pass results)
__global__ __launch_bounds__(256) void gemm_diff_c(const u16* __restrict__ M0, const u16* __restrict__ M1,
                                                   const u16* __restrict__ M2, const u16* __restrict__ M3,
                                                   const u16* __restrict__ Xr, u16* __restrict__ D,
                                                   long ldD, int Fp, int fin){
  __shared__ u16 lA[4096];
  __shared__ u16 lB[4096];
  f32x4 acc[4][4];
  int z = blockIdx.z;
  const u16* A = (z == 0) ? M0 : (z == 1) ? M1 : (z == 2) ? M2 : M3;
  long tM = (long)blockIdx.x * 128, tC = (long)blockIdx.y * 128;
  gemm_core(A, Xr, 2048, tM, tC, lA, lB, acc);

  int tid = threadIdx.x, wv = tid >> 6, lane = tid & 63;
  int q = lane >> 4, r16 = lane & 15, wm = wv & 1, wn = wv >> 1;
  int zb = (z + 1) * Fp + fin;
  #pragma unroll
  for (int i = 0; i < 4; i++){
    long gi = tM + wm*64 + i*16 + q*4;
    #pragma unroll
    for (int j = 0; j < 4; j++){
      int gc = (int)(tC + wn*64 + j*16 + r16);
      int b = gc >> 6, u = gc & 63;
      long rb = (long)b*2048 + gi;
      f32x4 v = acc[i][j];
      D[(rb+0)*ldD + zb + u] = f2bf(v[0]);
      D[(rb+1)*ldD + zb + u] = f2bf(v[1]);
      D[(rb+2)*ldD + zb + u] = f2bf(v[2]);
      D[(rb+3)*ldD + zb + u] = f2bf(v[3]);
    }
  }
}

// ---------- dense: OutT[c][i] = sum_k A[i,k]*Bt[c,k]  (f32 out) ----------
__global__ __launch_bounds__(256) void gemm_dense(const u16* __restrict__ A, const u16* __restrict__ Bt,
                                                  float* __restrict__ Out, int K, long ldOut){
  __shared__ u16 lA[4096];
  __shared__ u16 lB[4096];
  f32x4 acc[4][4];
  long tM = (long)blockIdx.x * 128, tC = (long)blockIdx.y * 128;
  gemm_core(A, Bt, K, tM, tC, lA, lB, acc);

  int tid = threadIdx.x, wv = tid >> 6, lane = tid & 63;
  int q = lane >> 4, r16 = lane & 15, wm = wv & 1, wn = wv >> 1;
  #pragma unroll
  for (int i = 0; i < 4; i++){
    long gi = tM + wm*64 + i*16 + q*4;
    #pragma unroll
    for (int j = 0; j < 4; j++){
      long gc = tC + wn*64 + j*16 + r16;
      *(f32x4*)(Out + gc*ldOut + gi) = acc[i][j];
    }
  }
}

// ---------- GRU epilogues ----------
// r = sigmoid(GT+bg); Xr[(b*64+u)*2048+n] = r*hx; D m0 col (coloff+u) = same
__global__ __launch_bounds__(256) void k_gate_ep(const float* __restrict__ GT, const float* __restrict__ bg,
                                                 const u16* __restrict__ X0T, u16* __restrict__ Xr,
                                                 u16* __restrict__ D,
                                                 int Fp, int rowoff, long ldD, int coloff){
  __shared__ u16 t[64*66];
  int b = blockIdx.x, n0 = blockIdx.y * 64;
  int tid = threadIdx.x;
  long bn0 = (long)b*2048 + n0;
  for (int e = tid; e < 4096; e += 256){
    int u = e >> 6, ni = e & 63;
    float r = sigf(GT[(long)u*65536 + bn0 + ni] + bg[u]);
    float hxv = bf2f(X0T[((long)b*Fp + rowoff + u)*2048 + n0 + ni]);
    u16 pv = f2bf(r * hxv);
    Xr[((long)b*64 + u)*2048 + n0 + ni] = pv;
    t[ni*66 + u] = pv;
  }
  __syncthreads();
  for (int e = tid; e < 4096; e += 256){
    int ni = e >> 6, u = e & 63;
    D[(bn0 + ni)*ldD + coloff + u] = t[ni*66 + u];
  }
}

__global__ __launch_bounds__(256) void k_cand_ep(const float* __restrict__ CT, const float* __restrict__ GT,
                                                 const float* __restrict__ bc, const float* __restrict__ bg,
                                                 const float* __restrict__ hx, float* __restrict__ hout,
                                                 u16* __restrict__ X0T_next, u16* __restrict__ Dnext,
                                                 const float* __restrict__ wproj, const float* __restrict__ bproj,
                                                 float* __restrict__ out){
  __shared__ u16 tc[64*66];
  __shared__ u16 tu[64*66];
  __shared__ u16 th[64*66];
  int b = blockIdx.x, n0 = blockIdx.y * 64;
  int tid = threadIdx.x;
  long bn0 = (long)b*2048 + n0;
  for (int e = tid; e < 4096; e += 256){
    int u = e >> 6, ni = e & 63;
    float cv = tanhf(CT[(long)u*65536 + bn0 + ni] + bc[u]);
    float uv = sigf(GT[(long)(64+u)*65536 + bn0 + ni] + bg[64+u]);
    tc[ni*66 + u] = f2bf(cv);
    tu[ni*66 + u] = f2bf(uv);
  }
  __syncthreads();
  int lane = tid & 63, wv = tid >> 6;
  for (int it = 0; it < 16; ++it){
    int ni = it*4 + wv, u = lane;
    float hxv = hx[((long)b*2048 + n0 + ni)*64 + u];
    float uv = bf2f(tu[ni*66 + u]), cv = bf2f(tc[ni*66 + u]);
    float h = uv*hxv + (1.f - uv)*cv;
    hout[((long)b*2048 + n0 + ni)*64 + u] = h;
    if (Dnext) Dnext[((long)(b*2048 + n0 + ni))*640 + u] = f2bf(h);
    th[ni*66 + u] = f2bf(h);
    if (wproj){
      float v = h * wproj[u];
      for (int off = 32; off; off >>= 1) v += __shfl_down(v, off, 64);
      if (lane == 0) out[(long)b*2048 + n0 + ni] = v + bproj[0];
    }
  }
  __syncthreads();
  if (X0T_next){
    for (int e = tid; e < 4096; e += 256){
      int u = e >> 6, ni = e & 63;
      X0T_next[((long)b*128 + u)*2048 + n0 + ni] = th[ni*66 + u];
    }
  }
}

// ---------- launch ----------
extern "C" void kernel_launch(void* const* d_in, const int* in_sizes, int n_in,
                              void* d_out, int out_size, void* d_ws, size_t ws_size,
                              hipStream_t stream){
  (void)in_sizes; (void)n_in; (void)out_size; (void)ws_size;
  const float* inputs = (const float*)d_in[0];
  const float* hidden = (const float*)d_in[1];
  const float* adj    = (const float*)d_in[2];
  const float* wg0 = (const float*)d_in[3];
  const float* bg0 = (const float*)d_in[4];
  const float* wc0 = (const float*)d_in[5];
  const float* bc0 = (const float*)d_in[6];
  const float* wg1 = (const float*)d_in[7];
  const float* bg1 = (const float*)d_in[8];
  const float* wc1 = (const float*)d_in[9];
  const float* bc1 = (const float*)d_in[10];
  const float* wp  = (const float*)d_in[11];
  const float* bp  = (const float*)d_in[12];
  float* out = (float*)d_out;

  char* p = (char*)d_ws;
  auto alloc = [&](size_t bytes)->char*{ char* r = p; p += (bytes + 255) & ~(size_t)255; return r; };
  float* inv_rs = (float*)alloc(2048*4);
  float* inv_cs = (float*)alloc(2048*4);
  float* cs     = (float*)alloc(2048*4);
  const size_t SB = (size_t)2048*2048*2;
  u16* S0  = (u16*)alloc(SB);
  u16* S0T = (u16*)alloc(SB);
  u16* S1  = (u16*)alloc(SB);
  u16* R   = (u16*)alloc(SB);
  u16* RT  = (u16*)alloc(SB);
  u16* V   = (u16*)alloc(SB);
  u16* W   = (u16*)alloc(SB);
  u16* X0a = (u16*)alloc((size_t)2304*2048*2);   // layer0 cat (XT layout, Fp=72)
  u16* X0b = (u16*)alloc((size_t)4096*2048*2);   // layer1 cat (Fp=128)
  u16* Xr  = (u16*)alloc(SB);                    // compact r*hx (2048 x 2048)
  u16* D   = (u16*)alloc((size_t)65536*640*2);
  float* GT = (float*)alloc((size_t)128*65536*4);
  float* CT = (float*)alloc((size_t)128*65536*4);
  u16* WTg0 = (u16*)alloc((size_t)128*384*2);
  u16* WTc0 = (u16*)alloc((size_t)128*384*2);
  u16* WTg1 = (u16*)alloc((size_t)128*640*2);
  u16* WTc1 = (u16*)alloc((size_t)128*640*2);

  const float* hid0 = hidden;
  const float* hid1 = hidden + (size_t)4194304;
  float* h0out = out + 65536;
  float* h1out = out + 65536 + 4194304;

  // ---- setup ----
  k_rowsum<<<2048, 256, 0, stream>>>(adj, inv_rs);
  k_zero<<<8, 256, 0, stream>>>(cs);
  k_colsum2<<<dim3(32,16), 256, 0, stream>>>(adj, cs);
  k_inv<<<8, 256, 0, stream>>>(cs, inv_cs);
  k_build_S0 <<<dim3(32,32), 256, 0, stream>>>(adj, inv_rs, S0);
  k_build_S0T<<<4096, 256, 0, stream>>>(adj, inv_rs, S0T);
  k_build_S1 <<<4096, 256, 0, stream>>>(adj, inv_cs, S1);
  k_packW<<<192, 256, 0, stream>>>(wg0, WTg0, 128, 65, 72, 384);
  k_packW<<<192, 256, 0, stream>>>(wc0, WTc0,  64, 65, 72, 384);
  k_packW<<<320, 256, 0, stream>>>(wg1, WTg1, 128, 128, 128, 640);
  k_packW<<<320, 256, 0, stream>>>(wc1, WTc1,  64, 128, 128, 640);
  k_hx_build<<<dim3(32,32), 256, 0, stream>>>(hid0, inputs, X0a, D, 72, 1, 384, 1, 1);

  // ---- precompute diffusion operators: R=S1@S0, V=2*S0^2-I, W=2*S1@R-S0 ----
  gemm_pre<<<dim3(16,16,2), 256, 0, stream>>>(S0T, S1, S0, R, RT, V);
  gemm_w  <<<dim3(16,16),   256, 0, stream>>>(RT, S1, S0, W);

  dim3 gD0(16, 18, 4), gD1(16, 32, 4), gDc(16, 16, 4), gDen(512, 1), gE(32, 32);

  // ---- layer 0 gate ----
  gemm_diff<72><<<gD0, 256, 0, stream>>>(S0, V, R, W, X0a, D, 384);
  gemm_dense<<<gDen, 256, 0, stream>>>(D, WTg0, GT, 384, 65536);
  k_gate_ep<<<gE, 256, 0, stream>>>(GT, bg0, X0a, Xr, D, 72, 1, 384, 1);

  // ---- layer 0 candidate (diffuse only r*hx; inp cols reused from gate pass) ----
  gemm_diff_c<<<gDc, 256, 0, stream>>>(S0, V, R, W, Xr, D, 384, 72, 1);
  gemm_dense<<<gDen, 256, 0, stream>>>(D, WTc0, CT, 384, 65536);
  k_cand_ep<<<gE, 256, 0, stream>>>(CT, GT, bc0, bg0, hid0, h0out, X0b, D, nullptr, nullptr, nullptr);

  // ---- layer 1 build ----
  k_hx_build<<<dim3(32,32), 256, 0, stream>>>(hid1, nullptr, X0b, D, 128, 64, 640, 64, 0);

  // ---- layer 1 gate ----
  gemm_diff<128><<<gD1, 256, 0, stream>>>(S0, V, R, W, X0b, D, 640);
  gemm_dense<<<gDen, 256, 0, stream>>>(D, WTg1, GT, 640, 65536);
  k_gate_ep<<<gE, 256, 0, stream>>>(GT, bg1, X0b, Xr, D, 128, 64, 640, 64);

  // ---- layer 1 candidate (diffuse only r*hx; h0 cols reused from gate pass) ----
  gemm_diff_c<<<gDc, 256, 0, stream>>>(S0, V, R, W, Xr, D, 640, 128, 64);
  gemm_dense<<<gDen, 256, 0, stream>>>(D, WTc1, CT, 640, 65536);
  k_cand_ep<<<gE, 256, 0, stream>>>(CT, GT, bc1, bg1, hid1, h1out, nullptr, nullptr, wp, bp, out);
}

// Round 5
// 802.305 us; speedup vs baseline: 1.7855x; 1.0588x over previous
//
#include <hip/hip_runtime.h>

typedef unsigned short u16;
typedef unsigned int u32;
typedef float f32x4 __attribute__((ext_vector_type(4)));
typedef __bf16 bf16x8 __attribute__((ext_vector_type(8)));

// ---------- helpers ----------
__device__ __forceinline__ u16 f2bf(float f){
  u32 u = __builtin_bit_cast(u32, f);
  u32 r = (u + 0x7fffu + ((u >> 16) & 1u)) >> 16;
  return (u16)r;
}
__device__ __forceinline__ float bf2f(u16 h){
  return __builtin_bit_cast(float, ((u32)h) << 16);
}
__device__ __forceinline__ void gl_lds16(const void* g, void* l){
  __builtin_amdgcn_global_load_lds((__attribute__((address_space(1))) void*)g,
                                   (__attribute__((address_space(3))) void*)l,
                                   16, 0, 0);
}
__device__ __forceinline__ float sigf(float x){ return 1.f/(1.f + __expf(-x)); }

// ---------- sums ----------
__global__ __launch_bounds__(256) void k_rowsum(const float* __restrict__ adj, float* __restrict__ inv_rs){
  int j = blockIdx.x; int tid = threadIdx.x;
  float s = 0.f;
  for (int i = tid; i < 2048; i += 256) s += adj[(long)j*2048 + i];
  for (int off = 32; off; off >>= 1) s += __shfl_down(s, off, 64);
  __shared__ float red[4];
  if ((tid & 63) == 0) red[tid >> 6] = s;
  __syncthreads();
  if (tid == 0){
    float t = red[0] + red[1] + red[2] + red[3];
    inv_rs[j] = 1.f / fmaxf(t, 1e-8f);
  }
}

__global__ __launch_bounds__(256) void k_zero(float* __restrict__ p){
  p[blockIdx.x*256 + threadIdx.x] = 0.f;
}

// 512 blocks: (32 col-groups x 16 row-groups), each sums a 64x128 tile, atomicAdd per col
__global__ __launch_bounds__(256) void k_colsum2(const float* __restrict__ adj, float* __restrict__ cs){
  int j0 = blockIdx.x * 64, i0 = blockIdx.y * 128;
  int jj = threadIdx.x & 63, w = threadIdx.x >> 6;
  float s = 0.f;
  for (int i = w; i < 128; i += 4) s += adj[(long)(i0+i)*2048 + j0 + jj];
  __shared__ float red[256];
  red[threadIdx.x] = s;
  __syncthreads();
  if (w == 0){
    float t = red[jj] + red[64+jj] + red[128+jj] + red[192+jj];
    atomicAdd(&cs[j0+jj], t);
  }
}

__global__ __launch_bounds__(256) void k_inv(const float* __restrict__ cs, float* __restrict__ inv_cs){
  int i = blockIdx.x*256 + threadIdx.x;
  inv_cs[i] = 1.f / fmaxf(cs[i], 1e-8f);
}

// S0[i][j] = adj[j][i] * inv_rs[j]  (LDS-tiled transpose)
__global__ __launch_bounds__(256) void k_build_S0(const float* __restrict__ adj, const float* __restrict__ inv_rs, u16* __restrict__ S0){
  __shared__ u16 t[64*66];
  int i0 = blockIdx.x * 64, j0 = blockIdx.y * 64;
  int tid = threadIdx.x;
  for (int e = tid; e < 4096; e += 256){
    int jj = e >> 6, ii = e & 63;
    t[jj*66 + ii] = f2bf(adj[(long)(j0+jj)*2048 + i0 + ii] * inv_rs[j0+jj]);
  }
  __syncthreads();
  for (int e = tid; e < 4096; e += 256){
    int ii = e >> 6, jj = e & 63;
    S0[(long)(i0+ii)*2048 + j0 + jj] = t[jj*66 + ii];
  }
}

// S0T[j][i] = adj[j][i] * inv_rs[j]  (row scale, no transpose)
__global__ __launch_bounds__(256) void k_build_S0T(const float* __restrict__ adj, const float* __restrict__ inv_rs, u16* __restrict__ S0T){
  long idx = ((long)blockIdx.x*256 + threadIdx.x) * 4;
  int j = (int)(idx >> 11);
  float s = inv_rs[j];
  float4 a = *(const float4*)(adj + idx);
  ushort4 o;
  o.x = f2bf(a.x * s); o.y = f2bf(a.y * s);
  o.z = f2bf(a.z * s); o.w = f2bf(a.w * s);
  *(ushort4*)(S0T + idx) = o;
}

// S1[i][j] = adj[i][j] * inv_cs[j]
__global__ __launch_bounds__(256) void k_build_S1(const float* __restrict__ adj, const float* __restrict__ inv_cs, u16* __restrict__ S1){
  long idx = ((long)blockIdx.x*256 + threadIdx.x) * 4;
  int j = (int)(idx & 2047);
  float4 a = *(const float4*)(adj + idx);
  float4 c = *(const float4*)(inv_cs + j);
  ushort4 o;
  o.x = f2bf(a.x * c.x); o.y = f2bf(a.y * c.y);
  o.z = f2bf(a.z * c.z); o.w = f2bf(a.w * c.w);
  *(ushort4*)(S1 + idx) = o;
}

// WT[o][k] = w[(f*5+m)*OUTr + o] for k=(m,f), zero-padded.  WT is 128 x Kd.
__global__ __launch_bounds__(256) void k_packW(const float* __restrict__ w, u16* __restrict__ WT,
                                               int OUTr, int F, int Fp, int Kd){
  int idx = blockIdx.x*256 + threadIdx.x;
  if (idx >= 128*Kd) return;
  int o = idx / Kd, k = idx - o*Kd;
  int m = k / Fp, f = k - m*Fp;
  float v = 0.f;
  if (o < OUTr && m < 5 && f < F) v = w[(long)(f*5 + m)*OUTr + o];
  WT[idx] = f2bf(v);
}

// hidden transpose into X0T rows (b, rowoff+u) and D cols (coloff+u); layer-0 extras: inp row/col + pads
__global__ __launch_bounds__(256) void k_hx_build(const float* __restrict__ hx, const float* __restrict__ inp,
                                                  u16* __restrict__ X0T, u16* __restrict__ D,
                                                  int Fp, int rowoff, long ldD, int coloff, int l0extras){
  __shared__ u16 t[64*66];
  int b = blockIdx.x, n0 = blockIdx.y * 64;
  int tid = threadIdx.x;
  const float* hb = hx + (long)b*2048*64;
  for (int e = tid; e < 4096; e += 256){
    int ni = e >> 6, u = e & 63;
    t[ni*66 + u] = f2bf(hb[(long)(n0+ni)*64 + u]);
  }
  __syncthreads();
  for (int e = tid; e < 4096; e += 256){
    int u = e >> 6, ni = e & 63;
    X0T[((long)b*Fp + rowoff + u)*2048 + n0 + ni] = t[ni*66 + u];
  }
  for (int e = tid; e < 4096; e += 256){
    int ni = e >> 6, u = e & 63;
    D[((long)(b*2048 + n0 + ni))*ldD + coloff + u] = t[ni*66 + u];
  }
  if (l0extras){
    if (tid < 64){
      u16 v = f2bf(inp[(long)b*2048 + n0 + tid]);
      X0T[((long)b*Fp)*2048 + n0 + tid] = v;
      D[((long)(b*2048 + n0 + tid))*ldD] = v;
    }
    for (int e = tid; e < 7*64; e += 256){
      int f = 65 + (e >> 6), ni = e & 63;
      X0T[((long)b*Fp + f)*2048 + n0 + ni] = 0;
    }
    for (int e = tid; e < 64*31; e += 256){
      int ni = e / 31, wc = e - ni*31;
      int col = (wc < 7) ? (65 + wc) : (353 + wc);   // {65..71, 360..383}
      D[((long)(b*2048 + n0 + ni))*ldD + col] = 0;
    }
  }
}

// ---------- GEMM core, BK=64: acc[i][j] += A-tile @ Bt-tile^T over K ----------
// LDS layout: linear 16B chunk L at byte L*16 (HW-forced by global_load_lds:
// wave-uniform base + lane*16). Row r = L>>3, stored slot = L&7 holds global
// chunk g = (L&7) ^ (r&7).  Fragment b128 reads at row m, k-half h:
// addr16 = m*8 + ((h*4+q) ^ (m&7)) -> 8 consecutive m cover all 8 bank-quads
// (conflict-free); 2-way alias across 16-lane halves is free (m136).
// BK=64 halves barrier crossings vs BK=32 (the ~20% vmcnt(0)+s_barrier drain).
__device__ __forceinline__ void gemm_core(const u16* __restrict__ A, const u16* __restrict__ Bt,
                                          int K, long tM, long tC,
                                          u16* lA, u16* lB, f32x4 (&acc)[4][4]){
  int tid = threadIdx.x;
  int wv = tid >> 6, lane = tid & 63;
  int q = lane >> 4, r16 = lane & 15;

  const u16* ga[4]; const u16* gb[4];
  u16* la[4]; u16* lb[4];
  #pragma unroll
  for (int it = 0; it < 4; it++){
    int L = it*256 + tid;
    int r = L >> 3, g = (L & 7) ^ (r & 7);
    ga[it] = A  + (tM + r)*(long)K + g*8;
    gb[it] = Bt + (tC + r)*(long)K + g*8;
    la[it] = lA + (it*256 + wv*64)*8;   // wave-uniform LDS base (u16 units)
    lb[it] = lB + (it*256 + wv*64)*8;
  }

  #pragma unroll
  for (int i = 0; i < 4; i++)
    #pragma unroll
    for (int j = 0; j < 4; j++){ acc[i][j][0]=0.f; acc[i][j][1]=0.f; acc[i][j][2]=0.f; acc[i][j][3]=0.f; }

  int wm = wv & 1, wn = wv >> 1;
  int aoff[4][2], boff[4][2];
  #pragma unroll
  for (int s = 0; s < 4; s++){
    int m = wm*64 + s*16 + r16;
    int n = wn*64 + s*16 + r16;
    #pragma unroll
    for (int h = 0; h < 2; h++){
      aoff[s][h] = (m*8 + ((h*4 + q) ^ (m & 7))) * 8;
      boff[s][h] = (n*8 + ((h*4 + q) ^ (n & 7))) * 8;
    }
  }

  for (int k0 = 0; k0 < K; k0 += 64){
    __syncthreads();
    #pragma unroll
    for (int it = 0; it < 4; it++){
      gl_lds16(ga[it] + k0, la[it]);
      gl_lds16(gb[it] + k0, lb[it]);
    }
    asm volatile("s_waitcnt vmcnt(0)" ::: "memory");
    __syncthreads();
    #pragma unroll
    for (int h = 0; h < 2; h++){
      bf16x8 af[4], bfr[4];
      #pragma unroll
      for (int s = 0; s < 4; s++){
        af[s]  = *(const bf16x8*)&lA[aoff[s][h]];
        bfr[s] = *(const bf16x8*)&lB[boff[s][h]];
      }
      #pragma unroll
      for (int i = 0; i < 4; i++)
        #pragma unroll
        for (int j = 0; j < 4; j++)
          acc[i][j] = __builtin_amdgcn_mfma_f32_16x16x32_bf16(af[i], bfr[j], acc[i][j], 0, 0, 0);
    }
  }
}

// ---------- precompute batch 1: z=0: R = S1@S0 (dual write R + RT); z=1: V = 2*S0^2 - I ----------
__global__ __launch_bounds__(256) void gemm_pre(const u16* __restrict__ S0T, const u16* __restrict__ S1,
                                                const u16* __restrict__ S0,
                                                u16* __restrict__ R, u16* __restrict__ RT, u16* __restrict__ V){
  __shared__ u16 lA[8192];
  __shared__ u16 lB[8192];
  f32x4 acc[4][4];
  const u16* Bt = (blockIdx.z == 0) ? S1 : S0;
  long tM = (long)blockIdx.x * 128, tC = (long)blockIdx.y * 128;
  gemm_core(S0T, Bt, 2048, tM, tC, lA, lB, acc);

  int tid = threadIdx.x, wv = tid >> 6, lane = tid & 63;
  int q = lane >> 4, r16 = lane & 15, wm = wv & 1, wn = wv >> 1;
  #pragma unroll
  for (int i = 0; i < 4; i++){
    long gi = tM + wm*64 + i*16 + q*4;
    #pragma unroll
    for (int j = 0; j < 4; j++){
      long gc = tC + wn*64 + j*16 + r16;
      f32x4 v = acc[i][j];
      if (blockIdx.z == 0){
        ushort4 o;
        o.x = f2bf(v[0]); o.y = f2bf(v[1]); o.z = f2bf(v[2]); o.w = f2bf(v[3]);
        *(ushort4*)(R + gc*2048 + gi) = o;
        RT[(gi+0)*2048 + gc] = o.x;
        RT[(gi+1)*2048 + gc] = o.y;
        RT[(gi+2)*2048 + gc] = o.z;
        RT[(gi+3)*2048 + gc] = o.w;
      } else {
        ushort4 o;
        #pragma unroll
        for (int e = 0; e < 4; e++){
          float x = 2.f*v[e] - ((gi+e) == gc ? 1.f : 0.f);
          ((u16*)&o)[e] = f2bf(x);
        }
        *(ushort4*)(V + gc*2048 + gi) = o;
      }
    }
  }
}

// ---------- precompute batch 2: W = 2*S1@R - S0 (A=RT, Bt=S1, aux=S0) ----------
__global__ __launch_bounds__(256) void gemm_w(const u16* __restrict__ RT, const u16* __restrict__ S1,
                                              const u16* __restrict__ S0, u16* __restrict__ W){
  __shared__ u16 lA[8192];
  __shared__ u16 lB[8192];
  f32x4 acc[4][4];
  long tM = (long)blockIdx.x * 128, tC = (long)blockIdx.y * 128;
  gemm_core(RT, S1, 2048, tM, tC, lA, lB, acc);

  int tid = threadIdx.x, wv = tid >> 6, lane = tid & 63;
  int q = lane >> 4, r16 = lane & 15, wm = wv & 1, wn = wv >> 1;
  #pragma unroll
  for (int i = 0; i < 4; i++){
    long gi = tM + wm*64 + i*16 + q*4;
    #pragma unroll
    for (int j = 0; j < 4; j++){
      long gc = tC + wn*64 + j*16 + r16;
      f32x4 v = acc[i][j];
      ushort4 x0 = *(const ushort4*)(S0 + gc*2048 + gi);
      ushort4 o;
      o.x = f2bf(2.f*v[0] - bf2f(x0.x));
      o.y = f2bf(2.f*v[1] - bf2f(x0.y));
      o.z = f2bf(2.f*v[2] - bf2f(x0.z));
      o.w = f2bf(2.f*v[3] - bf2f(x0.w));
      *(ushort4*)(W + gc*2048 + gi) = o;
    }
  }
}

// ---------- batched diffusion (gate: full cat X): z in {0..3} selects M in {S0,V,R,W}; writes D slice z+1 ----------
template<int FP>
__global__ __launch_bounds__(256) void gemm_diff(const u16* __restrict__ M0, const u16* __restrict__ M1,
                                                 const u16* __restrict__ M2, const u16* __restrict__ M3,
                                                 const u16* __restrict__ X, u16* __restrict__ D, long ldD){
  __shared__ u16 lA[8192];
  __shared__ u16 lB[8192];
  f32x4 acc[4][4];
  int z = blockIdx.z;
  const u16* A = (z == 0) ? M0 : (z == 1) ? M1 : (z == 2) ? M2 : M3;
  long tM = (long)blockIdx.x * 128, tC = (long)blockIdx.y * 128;
  gemm_core(A, X, 2048, tM, tC, lA, lB, acc);

  int tid = threadIdx.x, wv = tid >> 6, lane = tid & 63;
  int q = lane >> 4, r16 = lane & 15, wm = wv & 1, wn = wv >> 1;
  int zb = (z + 1) * FP;
  #pragma unroll
  for (int i = 0; i < 4; i++){
    long gi = tM + wm*64 + i*16 + q*4;
    #pragma unroll
    for (int j = 0; j < 4; j++){
      int gc = (int)(tC + wn*64 + j*16 + r16);
      int b = gc / FP, f = gc - b*FP;
      long rb = (long)b*2048 + gi;
      f32x4 v = acc[i][j];
      D[(rb+0)*ldD + zb + f] = f2bf(v[0]);
      D[(rb+1)*ldD + zb + f] = f2bf(v[1]);
      D[(rb+2)*ldD + zb + f] = f2bf(v[2]);
      D[(rb+3)*ldD + zb + f] = f2bf(v[3]);
    }
  }
}

// ---------- candidate diffusion: only the r*hx block (Xr: 2048 x 2048, rows = b*64+u) ----------
// writes D col (z+1)*Fp + Fin + u   (inp-part cols already hold gate-pass results)
__global__ __launch_bounds__(256) void gemm_diff_c(const u16* __restrict__ M0, const u16* __restrict__ M1,
                                                   const u16* __restrict__ M2, const u16* __restrict__ M3,
                                                   const u16* __restrict__ Xr, u16* __restrict__ D,
                                                   long ldD, int Fp, int fin){
  __shared__ u16 lA[8192];
  __shared__ u16 lB[8192];
  f32x4 acc[4][4];
  int z = blockIdx.z;
  const u16* A = (z == 0) ? M0 : (z == 1) ? M1 : (z == 2) ? M2 : M3;
  long tM = (long)blockIdx.x * 128, tC = (long)blockIdx.y * 128;
  gemm_core(A, Xr, 2048, tM, tC, lA, lB, acc);

  int tid = threadIdx.x, wv = tid >> 6, lane = tid & 63;
  int q = lane >> 4, r16 = lane & 15, wm = wv & 1, wn = wv >> 1;
  int zb = (z + 1) * Fp + fin;
  #pragma unroll
  for (int i = 0; i < 4; i++){
    long gi = tM + wm*64 + i*16 + q*4;
    #pragma unroll
    for (int j = 0; j < 4; j++){
      int gc = (int)(tC + wn*64 + j*16 + r16);
      int b = gc >> 6, u = gc & 63;
      long rb = (long)b*2048 + gi;
      f32x4 v = acc[i][j];
      D[(rb+0)*ldD + zb + u] = f2bf(v[0]);
      D[(rb+1)*ldD + zb + u] = f2bf(v[1]);
      D[(rb+2)*ldD + zb + u] = f2bf(v[2]);
      D[(rb+3)*ldD + zb + u] = f2bf(v[3]);
    }
  }
}

// ---------- dense: OutT[c][i] = sum_k A[i,k]*Bt[c,k]  (f32 out) ----------
__global__ __launch_bounds__(256) void gemm_dense(const u16* __restrict__ A, const u16* __restrict__ Bt,
                                                  float* __restrict__ Out, int K, long ldOut){
  __shared__ u16 lA[8192];
  __shared__ u16 lB[8192];
  f32x4 acc[4][4];
  long tM = (long)blockIdx.x * 128, tC = (long)blockIdx.y * 128;
  gemm_core(A, Bt, K, tM, tC, lA, lB, acc);

  int tid = threadIdx.x, wv = tid >> 6, lane = tid & 63;
  int q = lane >> 4, r16 = lane & 15, wm = wv & 1, wn = wv >> 1;
  #pragma unroll
  for (int i = 0; i < 4; i++){
    long gi = tM + wm*64 + i*16 + q*4;
    #pragma unroll
    for (int j = 0; j < 4; j++){
      long gc = tC + wn*64 + j*16 + r16;
      *(f32x4*)(Out + gc*ldOut + gi) = acc[i][j];
    }
  }
}

// ---------- GRU epilogues ----------
// r = sigmoid(GT+bg); Xr[(b*64+u)*2048+n] = r*hx; D m0 col (coloff+u) = same
__global__ __launch_bounds__(256) void k_gate_ep(const float* __restrict__ GT, const float* __restrict__ bg,
                                                 const u16* __restrict__ X0T, u16* __restrict__ Xr,
                                                 u16* __restrict__ D,
                                                 int Fp, int rowoff, long ldD, int coloff){
  __shared__ u16 t[64*66];
  int b = blockIdx.x, n0 = blockIdx.y * 64;
  int tid = threadIdx.x;
  long bn0 = (long)b*2048 + n0;
  for (int e = tid; e < 4096; e += 256){
    int u = e >> 6, ni = e & 63;
    float r = sigf(GT[(long)u*65536 + bn0 + ni] + bg[u]);
    float hxv = bf2f(X0T[((long)b*Fp + rowoff + u)*2048 + n0 + ni]);
    u16 pv = f2bf(r * hxv);
    Xr[((long)b*64 + u)*2048 + n0 + ni] = pv;
    t[ni*66 + u] = pv;
  }
  __syncthreads();
  for (int e = tid; e < 4096; e += 256){
    int ni = e >> 6, u = e & 63;
    D[(bn0 + ni)*ldD + coloff + u] = t[ni*66 + u];
  }
}

__global__ __launch_bounds__(256) void k_cand_ep(const float* __restrict__ CT, const float* __restrict__ GT,
                                                 const float* __restrict__ bc, const float* __restrict__ bg,
                                                 const float* __restrict__ hx, float* __restrict__ hout,
                                                 u16* __restrict__ X0T_next, u16* __restrict__ Dnext,
                                                 const float* __restrict__ wproj, const float* __restrict__ bproj,
                                                 float* __restrict__ out){
  __shared__ u16 tc[64*66];
  __shared__ u16 tu[64*66];
  __shared__ u16 th[64*66];
  int b = blockIdx.x, n0 = blockIdx.y * 64;
  int tid = threadIdx.x;
  long bn0 = (long)b*2048 + n0;
  for (int e = tid; e < 4096; e += 256){
    int u = e >> 6, ni = e & 63;
    float cv = tanhf(CT[(long)u*65536 + bn0 + ni] + bc[u]);
    float uv = sigf(GT[(long)(64+u)*65536 + bn0 + ni] + bg[64+u]);
    tc[ni*66 + u] = f2bf(cv);
    tu[ni*66 + u] = f2bf(uv);
  }
  __syncthreads();
  int lane = tid & 63, wv = tid >> 6;
  for (int it = 0; it < 16; ++it){
    int ni = it*4 + wv, u = lane;
    float hxv = hx[((long)b*2048 + n0 + ni)*64 + u];
    float uv = bf2f(tu[ni*66 + u]), cv = bf2f(tc[ni*66 + u]);
    float h = uv*hxv + (1.f - uv)*cv;
    hout[((long)b*2048 + n0 + ni)*64 + u] = h;
    if (Dnext) Dnext[((long)(b*2048 + n0 + ni))*640 + u] = f2bf(h);
    th[ni*66 + u] = f2bf(h);
    if (wproj){
      float v = h * wproj[u];
      for (int off = 32; off; off >>= 1) v += __shfl_down(v, off, 64);
      if (lane == 0) out[(long)b*2048 + n0 + ni] = v + bproj[0];
    }
  }
  __syncthreads();
  if (X0T_next){
    for (int e = tid; e < 4096; e += 256){
      int u = e >> 6, ni = e & 63;
      X0T_next[((long)b*128 + u)*2048 + n0 + ni] = th[ni*66 + u];
    }
  }
}

// ---------- launch ----------
extern "C" void kernel_launch(void* const* d_in, const int* in_sizes, int n_in,
                              void* d_out, int out_size, void* d_ws, size_t ws_size,
                              hipStream_t stream){
  (void)in_sizes; (void)n_in; (void)out_size; (void)ws_size;
  const float* inputs = (const float*)d_in[0];
  const float* hidden = (const float*)d_in[1];
  const float* adj    = (const float*)d_in[2];
  const float* wg0 = (const float*)d_in[3];
  const float* bg0 = (const float*)d_in[4];
  const float* wc0 = (const float*)d_in[5];
  const float* bc0 = (const float*)d_in[6];
  const float* wg1 = (const float*)d_in[7];
  const float* bg1 = (const float*)d_in[8];
  const float* wc1 = (const float*)d_in[9];
  const float* bc1 = (const float*)d_in[10];
  const float* wp  = (const float*)d_in[11];
  const float* bp  = (const float*)d_in[12];
  float* out = (float*)d_out;

  char* p = (char*)d_ws;
  auto alloc = [&](size_t bytes)->char*{ char* r = p; p += (bytes + 255) & ~(size_t)255; return r; };
  float* inv_rs = (float*)alloc(2048*4);
  float* inv_cs = (float*)alloc(2048*4);
  float* cs     = (float*)alloc(2048*4);
  const size_t SB = (size_t)2048*2048*2;
  u16* S0  = (u16*)alloc(SB);
  u16* S0T = (u16*)alloc(SB);
  u16* S1  = (u16*)alloc(SB);
  u16* R   = (u16*)alloc(SB);
  u16* RT  = (u16*)alloc(SB);
  u16* V   = (u16*)alloc(SB);
  u16* W   = (u16*)alloc(SB);
  u16* X0a = (u16*)alloc((size_t)2304*2048*2);   // layer0 cat (XT layout, Fp=72)
  u16* X0b = (u16*)alloc((size_t)4096*2048*2);   // layer1 cat (Fp=128)
  u16* Xr  = (u16*)alloc(SB);                    // compact r*hx (2048 x 2048)
  u16* D   = (u16*)alloc((size_t)65536*640*2);
  float* GT = (float*)alloc((size_t)128*65536*4);
  float* CT = (float*)alloc((size_t)128*65536*4);
  u16* WTg0 = (u16*)alloc((size_t)128*384*2);
  u16* WTc0 = (u16*)alloc((size_t)128*384*2);
  u16* WTg1 = (u16*)alloc((size_t)128*640*2);
  u16* WTc1 = (u16*)alloc((size_t)128*640*2);

  const float* hid0 = hidden;
  const float* hid1 = hidden + (size_t)4194304;
  float* h0out = out + 65536;
  float* h1out = out + 65536 + 4194304;

  // ---- setup ----
  k_rowsum<<<2048, 256, 0, stream>>>(adj, inv_rs);
  k_zero<<<8, 256, 0, stream>>>(cs);
  k_colsum2<<<dim3(32,16), 256, 0, stream>>>(adj, cs);
  k_inv<<<8, 256, 0, stream>>>(cs, inv_cs);
  k_build_S0 <<<dim3(32,32), 256, 0, stream>>>(adj, inv_rs, S0);
  k_build_S0T<<<4096, 256, 0, stream>>>(adj, inv_rs, S0T);
  k_build_S1 <<<4096, 256, 0, stream>>>(adj, inv_cs, S1);
  k_packW<<<192, 256, 0, stream>>>(wg0, WTg0, 128, 65, 72, 384);
  k_packW<<<192, 256, 0, stream>>>(wc0, WTc0,  64, 65, 72, 384);
  k_packW<<<320, 256, 0, stream>>>(wg1, WTg1, 128, 128, 128, 640);
  k_packW<<<320, 256, 0, stream>>>(wc1, WTc1,  64, 128, 128, 640);
  k_hx_build<<<dim3(32,32), 256, 0, stream>>>(hid0, inputs, X0a, D, 72, 1, 384, 1, 1);

  // ---- precompute diffusion operators: R=S1@S0, V=2*S0^2-I, W=2*S1@R-S0 ----
  gemm_pre<<<dim3(16,16,2), 256, 0, stream>>>(S0T, S1, S0, R, RT, V);
  gemm_w  <<<dim3(16,16),   256, 0, stream>>>(RT, S1, S0, W);

  dim3 gD0(16, 18, 4), gD1(16, 32, 4), gDc(16, 16, 4), gDen(512, 1), gE(32, 32);

  // ---- layer 0 gate ----
  gemm_diff<72><<<gD0, 256, 0, stream>>>(S0, V, R, W, X0a, D, 384);
  gemm_dense<<<gDen, 256, 0, stream>>>(D, WTg0, GT, 384, 65536);
  k_gate_ep<<<gE, 256, 0, stream>>>(GT, bg0, X0a, Xr, D, 72, 1, 384, 1);

  // ---- layer 0 candidate (diffuse only r*hx; inp cols reused from gate pass) ----
  gemm_diff_c<<<gDc, 256, 0, stream>>>(S0, V, R, W, Xr, D, 384, 72, 1);
  gemm_dense<<<gDen, 256, 0, stream>>>(D, WTc0, CT, 384, 65536);
  k_cand_ep<<<gE, 256, 0, stream>>>(CT, GT, bc0, bg0, hid0, h0out, X0b, D, nullptr, nullptr, nullptr);

  // ---- layer 1 build ----
  k_hx_build<<<dim3(32,32), 256, 0, stream>>>(hid1, nullptr, X0b, D, 128, 64, 640, 64, 0);

  // ---- layer 1 gate ----
  gemm_diff<128><<<gD1, 256, 0, stream>>>(S0, V, R, W, X0b, D, 640);
  gemm_dense<<<gDen, 256, 0, stream>>>(D, WTg1, GT, 640, 65536);
  k_gate_ep<<<gE, 256, 0, stream>>>(GT, bg1, X0b, Xr, D, 128, 64, 640, 64);

  // ---- layer 1 candidate (diffuse only r*hx; h0 cols reused from gate pass) ----
  gemm_diff_c<<<gDc, 256, 0, stream>>>(S0, V, R, W, Xr, D, 640, 128, 64);
  gemm_dense<<<gDen, 256, 0, stream>>>(D, WTc1, CT, 640, 65536);
  k_cand_ep<<<gE, 256, 0, stream>>>(CT, GT, bc1, bg1, hid1, h1out, nullptr, nullptr, wp, bp, out);
}

// Round 6
// 623.774 us; speedup vs baseline: 2.2966x; 1.2862x over previous
//
#include <hip/hip_runtime.h>

typedef unsigned short u16;
typedef unsigned char u8;
typedef unsigned int u32;
typedef float f32x4 __attribute__((ext_vector_type(4)));
typedef __bf16 bf16x8 __attribute__((ext_vector_type(8)));
typedef int i32x8 __attribute__((ext_vector_type(8)));

// MX scale bytes (E8M0: 2^(b-127)): A-side 2^-8 (S matrices quantized x256), B-side 1.0
#define SCL_A 0x77777777
#define SCL_B 0x7F7F7F7F

// ---------- helpers ----------
__device__ __forceinline__ u16 f2bf(float f){
  u32 u = __builtin_bit_cast(u32, f);
  u32 r = (u + 0x7fffu + ((u >> 16) & 1u)) >> 16;
  return (u16)r;
}
__device__ __forceinline__ float bf2f(u16 h){
  return __builtin_bit_cast(float, ((u32)h) << 16);
}
__device__ __forceinline__ u8 f2e4(float x){
  return (u8)(__builtin_amdgcn_cvt_pk_fp8_f32(x, x, 0, false) & 0xff);
}
__device__ __forceinline__ u32 pack4_e4(float a, float b, float c, float d){
  int w = __builtin_amdgcn_cvt_pk_fp8_f32(a, b, 0, false);
  w = __builtin_amdgcn_cvt_pk_fp8_f32(c, d, w, true);
  return (u32)w;
}
__device__ __forceinline__ void gl_lds16(const void* g, void* l){
  __builtin_amdgcn_global_load_lds((__attribute__((address_space(1))) void*)g,
                                   (__attribute__((address_space(3))) void*)l,
                                   16, 0, 0);
}
__device__ __forceinline__ float sigf(float x){ return 1.f/(1.f + __expf(-x)); }

// ---------- sums ----------
__global__ __launch_bounds__(256) void k_rowsum(const float* __restrict__ adj, float* __restrict__ inv_rs){
  int j = blockIdx.x; int tid = threadIdx.x;
  float s = 0.f;
  for (int i = tid; i < 2048; i += 256) s += adj[(long)j*2048 + i];
  for (int off = 32; off; off >>= 1) s += __shfl_down(s, off, 64);
  __shared__ float red[4];
  if ((tid & 63) == 0) red[tid >> 6] = s;
  __syncthreads();
  if (tid == 0){
    float t = red[0] + red[1] + red[2] + red[3];
    inv_rs[j] = 1.f / fmaxf(t, 1e-8f);
  }
}

__global__ __launch_bounds__(256) void k_zero(float* __restrict__ p){
  p[blockIdx.x*256 + threadIdx.x] = 0.f;
}

__global__ __launch_bounds__(256) void k_colsum2(const float* __restrict__ adj, float* __restrict__ cs){
  int j0 = blockIdx.x * 64, i0 = blockIdx.y * 128;
  int jj = threadIdx.x & 63, w = threadIdx.x >> 6;
  float s = 0.f;
  for (int i = w; i < 128; i += 4) s += adj[(long)(i0+i)*2048 + j0 + jj];
  __shared__ float red[256];
  red[threadIdx.x] = s;
  __syncthreads();
  if (w == 0){
    float t = red[jj] + red[64+jj] + red[128+jj] + red[192+jj];
    atomicAdd(&cs[j0+jj], t);
  }
}

__global__ __launch_bounds__(256) void k_inv(const float* __restrict__ cs, float* __restrict__ inv_cs){
  int i = blockIdx.x*256 + threadIdx.x;
  inv_cs[i] = 1.f / fmaxf(cs[i], 1e-8f);
}

// S0[i][j] = adj[j][i] * inv_rs[j]  (LDS-tiled transpose)
__global__ __launch_bounds__(256) void k_build_S0(const float* __restrict__ adj, const float* __restrict__ inv_rs, u16* __restrict__ S0){
  __shared__ u16 t[64*66];
  int i0 = blockIdx.x * 64, j0 = blockIdx.y * 64;
  int tid = threadIdx.x;
  for (int e = tid; e < 4096; e += 256){
    int jj = e >> 6, ii = e & 63;
    t[jj*66 + ii] = f2bf(adj[(long)(j0+jj)*2048 + i0 + ii] * inv_rs[j0+jj]);
  }
  __syncthreads();
  for (int e = tid; e < 4096; e += 256){
    int ii = e >> 6, jj = e & 63;
    S0[(long)(i0+ii)*2048 + j0 + jj] = t[jj*66 + ii];
  }
}

// S0T[j][i] = adj[j][i] * inv_rs[j]
__global__ __launch_bounds__(256) void k_build_S0T(const float* __restrict__ adj, const float* __restrict__ inv_rs, u16* __restrict__ S0T){
  long idx = ((long)blockIdx.x*256 + threadIdx.x) * 4;
  int j = (int)(idx >> 11);
  float s = inv_rs[j];
  float4 a = *(const float4*)(adj + idx);
  ushort4 o;
  o.x = f2bf(a.x * s); o.y = f2bf(a.y * s);
  o.z = f2bf(a.z * s); o.w = f2bf(a.w * s);
  *(ushort4*)(S0T + idx) = o;
}

// S1[i][j] = adj[i][j] * inv_cs[j]
__global__ __launch_bounds__(256) void k_build_S1(const float* __restrict__ adj, const float* __restrict__ inv_cs, u16* __restrict__ S1){
  long idx = ((long)blockIdx.x*256 + threadIdx.x) * 4;
  int j = (int)(idx & 2047);
  float4 a = *(const float4*)(adj + idx);
  float4 c = *(const float4*)(inv_cs + j);
  ushort4 o;
  o.x = f2bf(a.x * c.x); o.y = f2bf(a.y * c.y);
  o.z = f2bf(a.z * c.z); o.w = f2bf(a.w * c.w);
  *(ushort4*)(S1 + idx) = o;
}

// bf16 -> e4m3 with scale (8 elems/thread)
__global__ __launch_bounds__(256) void k_q8(const u16* __restrict__ src, u8* __restrict__ dst, float scale){
  long i = ((long)blockIdx.x*256 + threadIdx.x) * 8;
  ushort4 s0 = *(const ushort4*)(src + i);
  ushort4 s1 = *(const ushort4*)(src + i + 4);
  u32 w0 = pack4_e4(bf2f(s0.x)*scale, bf2f(s0.y)*scale, bf2f(s0.z)*scale, bf2f(s0.w)*scale);
  u32 w1 = pack4_e4(bf2f(s1.x)*scale, bf2f(s1.y)*scale, bf2f(s1.z)*scale, bf2f(s1.w)*scale);
  uint2 o; o.x = w0; o.y = w1;
  *(uint2*)(dst + i) = o;
}

// WT[o][k] = w[(f*5+m)*OUTr + o] for k=(m,f), zero-padded.  WT is 128 x Kd.
__global__ __launch_bounds__(256) void k_packW(const float* __restrict__ w, u16* __restrict__ WT,
                                               int OUTr, int F, int Fp, int Kd){
  int idx = blockIdx.x*256 + threadIdx.x;
  if (idx >= 128*Kd) return;
  int o = idx / Kd, k = idx - o*Kd;
  int m = k / Fp, f = k - m*Fp;
  float v = 0.f;
  if (o < OUTr && m < 5 && f < F) v = w[(long)(f*5 + m)*OUTr + o];
  WT[idx] = f2bf(v);
}

// hidden (f32) -> fp8 X0T rows (b, rowoff+u) + bf16 D cols (coloff+u); layer-0 extras: inp + pads
__global__ __launch_bounds__(256) void k_hx_build(const float* __restrict__ hx, const float* __restrict__ inp,
                                                  u8* __restrict__ X0T, u16* __restrict__ D,
                                                  int Fp, int rowoff, long ldD, int coloff, int l0extras){
  __shared__ float t[64*66];
  int b = blockIdx.x, n0 = blockIdx.y * 64;
  int tid = threadIdx.x;
  const float* hb = hx + (long)b*2048*64;
  long bn0 = (long)b*2048 + n0;
  for (int e = tid; e < 4096; e += 256){
    int u = e & 63, ni = e >> 6;            // lane->u: f32 read coalesced
    t[ni*66 + u] = hb[(long)(n0+ni)*64 + u];
  }
  __syncthreads();
  for (int e = tid; e < 4096; e += 256){
    int u = e >> 6, ni = e & 63;            // lane->ni: fp8 row write coalesced
    X0T[((long)b*Fp + rowoff + u)*2048 + n0 + ni] = f2e4(t[ni*66 + u]);
  }
  for (int e = tid; e < 4096; e += 256){
    int ni = e >> 6, u = e & 63;            // lane->u: D col write coalesced
    D[(bn0 + ni)*ldD + coloff + u] = f2bf(t[ni*66 + u]);
  }
  if (l0extras){
    if (tid < 64){
      float v = inp[(long)b*2048 + n0 + tid];
      X0T[((long)b*Fp)*2048 + n0 + tid] = f2e4(v);
      D[(bn0 + tid)*ldD] = f2bf(v);
    }
    for (int e = tid; e < 7*64; e += 256){
      int f = 65 + (e >> 6), ni = e & 63;
      X0T[((long)b*Fp + f)*2048 + n0 + ni] = 0;
    }
    for (int e = tid; e < 64*31; e += 256){
      int ni = e / 31, wc = e - ni*31;
      int col = (wc < 7) ? (65 + wc) : (353 + wc);   // {65..71, 360..383}
      D[(bn0 + ni)*ldD + col] = 0;
    }
  }
}

// ---------- bf16 GEMM core, BK=64 (precompute + dense) ----------
__device__ __forceinline__ void gemm_core(const u16* __restrict__ A, const u16* __restrict__ Bt,
                                          int K, long tM, long tC,
                                          u16* lA, u16* lB, f32x4 (&acc)[4][4]){
  int tid = threadIdx.x;
  int wv = tid >> 6, lane = tid & 63;
  int q = lane >> 4, r16 = lane & 15;

  const u16* ga[4]; const u16* gb[4];
  u16* la[4]; u16* lb[4];
  #pragma unroll
  for (int it = 0; it < 4; it++){
    int L = it*256 + tid;
    int r = L >> 3, g = (L & 7) ^ (r & 7);
    ga[it] = A  + (tM + r)*(long)K + g*8;
    gb[it] = Bt + (tC + r)*(long)K + g*8;
    la[it] = lA + (it*256 + wv*64)*8;
    lb[it] = lB + (it*256 + wv*64)*8;
  }

  #pragma unroll
  for (int i = 0; i < 4; i++)
    #pragma unroll
    for (int j = 0; j < 4; j++){ acc[i][j][0]=0.f; acc[i][j][1]=0.f; acc[i][j][2]=0.f; acc[i][j][3]=0.f; }

  int wm = wv & 1, wn = wv >> 1;
  int aoff[4][2], boff[4][2];
  #pragma unroll
  for (int s = 0; s < 4; s++){
    int m = wm*64 + s*16 + r16;
    int n = wn*64 + s*16 + r16;
    #pragma unroll
    for (int h = 0; h < 2; h++){
      aoff[s][h] = (m*8 + ((h*4 + q) ^ (m & 7))) * 8;
      boff[s][h] = (n*8 + ((h*4 + q) ^ (n & 7))) * 8;
    }
  }

  for (int k0 = 0; k0 < K; k0 += 64){
    __syncthreads();
    #pragma unroll
    for (int it = 0; it < 4; it++){
      gl_lds16(ga[it] + k0, la[it]);
      gl_lds16(gb[it] + k0, lb[it]);
    }
    asm volatile("s_waitcnt vmcnt(0)" ::: "memory");
    __syncthreads();
    #pragma unroll
    for (int h = 0; h < 2; h++){
      bf16x8 af[4], bfr[4];
      #pragma unroll
      for (int s = 0; s < 4; s++){
        af[s]  = *(const bf16x8*)&lA[aoff[s][h]];
        bfr[s] = *(const bf16x8*)&lB[boff[s][h]];
      }
      #pragma unroll
      for (int i = 0; i < 4; i++)
        #pragma unroll
        for (int j = 0; j < 4; j++)
          acc[i][j] = __builtin_amdgcn_mfma_f32_16x16x32_bf16(af[i], bfr[j], acc[i][j], 0, 0, 0);
    }
  }
}

// ---------- fp8 MX GEMM core, BK=128 elements (=bytes) ----------
// Same staging/swizzle scheme in bytes: chunk L -> row r=L>>3, slot L&7 holds
// global chunk g=(L&7)^(r&7). Frag: lane(m=lane&15,q=lane>>4) reads 32 bytes
// (k = q*32..q*32+31) as two b128 at slots (2q+e)^(m&7) -> 8-lane issue groups
// cover all 8 bank-quads (conflict-free). One mfma_scale per 16x16x128.
__device__ __forceinline__ void gemm_core8(const u8* __restrict__ A, const u8* __restrict__ Bt,
                                           int K, long tM, long tC,
                                           u8* lA, u8* lB, f32x4 (&acc)[4][4]){
  int tid = threadIdx.x;
  int wv = tid >> 6, lane = tid & 63;
  int q = lane >> 4, r16 = lane & 15;

  const u8* ga[4]; const u8* gb[4];
  u8* la[4]; u8* lb[4];
  #pragma unroll
  for (int it = 0; it < 4; it++){
    int L = it*256 + tid;
    int r = L >> 3, g = (L & 7) ^ (r & 7);
    ga[it] = A  + (tM + r)*(long)K + g*16;
    gb[it] = Bt + (tC + r)*(long)K + g*16;
    la[it] = lA + (it*256 + wv*64)*16;
    lb[it] = lB + (it*256 + wv*64)*16;
  }

  #pragma unroll
  for (int i = 0; i < 4; i++)
    #pragma unroll
    for (int j = 0; j < 4; j++){ acc[i][j][0]=0.f; acc[i][j][1]=0.f; acc[i][j][2]=0.f; acc[i][j][3]=0.f; }

  int wm = wv & 1, wn = wv >> 1;
  int aoff[4][2], boff[4][2];
  #pragma unroll
  for (int s = 0; s < 4; s++){
    int m = wm*64 + s*16 + r16;
    int n = wn*64 + s*16 + r16;
    #pragma unroll
    for (int e = 0; e < 2; e++){
      aoff[s][e] = m*128 + ((2*q + e) ^ (m & 7)) * 16;
      boff[s][e] = n*128 + ((2*q + e) ^ (n & 7)) * 16;
    }
  }

  for (int k0 = 0; k0 < K; k0 += 128){
    __syncthreads();
    #pragma unroll
    for (int it = 0; it < 4; it++){
      gl_lds16(ga[it] + k0, la[it]);
      gl_lds16(gb[it] + k0, lb[it]);
    }
    asm volatile("s_waitcnt vmcnt(0)" ::: "memory");
    __syncthreads();
    i32x8 af[4], bfr[4];
    #pragma unroll
    for (int s = 0; s < 4; s++){
      uint4 a0 = *(const uint4*)&lA[aoff[s][0]];
      uint4 a1 = *(const uint4*)&lA[aoff[s][1]];
      i32x8 av; av[0]=a0.x; av[1]=a0.y; av[2]=a0.z; av[3]=a0.w; av[4]=a1.x; av[5]=a1.y; av[6]=a1.z; av[7]=a1.w;
      af[s] = av;
      uint4 b0 = *(const uint4*)&lB[boff[s][0]];
      uint4 b1 = *(const uint4*)&lB[boff[s][1]];
      i32x8 bv; bv[0]=b0.x; bv[1]=b0.y; bv[2]=b0.z; bv[3]=b0.w; bv[4]=b1.x; bv[5]=b1.y; bv[6]=b1.z; bv[7]=b1.w;
      bfr[s] = bv;
    }
    #pragma unroll
    for (int i = 0; i < 4; i++)
      #pragma unroll
      for (int j = 0; j < 4; j++)
        acc[i][j] = __builtin_amdgcn_mfma_scale_f32_16x16x128_f8f6f4(
                      af[i], bfr[j], acc[i][j], 0, 0, 0, SCL_A, 0, SCL_B);
  }
}

// ---------- precompute: z=0: R=S1@S0 -> RT(bf16) + Rq(e4m3 x256); z=1: V=2*S0^2-I -> Vq ----------
__global__ __launch_bounds__(256) void gemm_pre(const u16* __restrict__ S0T, const u16* __restrict__ S1,
                                                const u16* __restrict__ S0,
                                                u8* __restrict__ Rq, u16* __restrict__ RT, u8* __restrict__ Vq){
  __shared__ u16 lA[8192];
  __shared__ u16 lB[8192];
  f32x4 acc[4][4];
  const u16* Bt = (blockIdx.z == 0) ? S1 : S0;
  long tM = (long)blockIdx.x * 128, tC = (long)blockIdx.y * 128;
  gemm_core(S0T, Bt, 2048, tM, tC, lA, lB, acc);

  int tid = threadIdx.x, wv = tid >> 6, lane = tid & 63;
  int q = lane >> 4, r16 = lane & 15, wm = wv & 1, wn = wv >> 1;
  #pragma unroll
  for (int i = 0; i < 4; i++){
    long gi = tM + wm*64 + i*16 + q*4;
    #pragma unroll
    for (int j = 0; j < 4; j++){
      long gc = tC + wn*64 + j*16 + r16;
      f32x4 v = acc[i][j];
      if (blockIdx.z == 0){
        *(u32*)(Rq + gc*2048 + gi) = pack4_e4(v[0]*256.f, v[1]*256.f, v[2]*256.f, v[3]*256.f);
        RT[(gi+0)*2048 + gc] = f2bf(v[0]);
        RT[(gi+1)*2048 + gc] = f2bf(v[1]);
        RT[(gi+2)*2048 + gc] = f2bf(v[2]);
        RT[(gi+3)*2048 + gc] = f2bf(v[3]);
      } else {
        float x0 = 2.f*v[0] - ((gi+0) == gc ? 1.f : 0.f);
        float x1 = 2.f*v[1] - ((gi+1) == gc ? 1.f : 0.f);
        float x2 = 2.f*v[2] - ((gi+2) == gc ? 1.f : 0.f);
        float x3 = 2.f*v[3] - ((gi+3) == gc ? 1.f : 0.f);
        *(u32*)(Vq + gc*2048 + gi) = pack4_e4(x0*256.f, x1*256.f, x2*256.f, x3*256.f);
      }
    }
  }
}

// ---------- precompute: W = 2*S1@R - S0 -> Wq(e4m3 x256) ----------
__global__ __launch_bounds__(256) void gemm_w(const u16* __restrict__ RT, const u16* __restrict__ S1,
                                              const u16* __restrict__ S0, u8* __restrict__ Wq){
  __shared__ u16 lA[8192];
  __shared__ u16 lB[8192];
  f32x4 acc[4][4];
  long tM = (long)blockIdx.x * 128, tC = (long)blockIdx.y * 128;
  gemm_core(RT, S1, 2048, tM, tC, lA, lB, acc);

  int tid = threadIdx.x, wv = tid >> 6, lane = tid & 63;
  int q = lane >> 4, r16 = lane & 15, wm = wv & 1, wn = wv >> 1;
  #pragma unroll
  for (int i = 0; i < 4; i++){
    long gi = tM + wm*64 + i*16 + q*4;
    #pragma unroll
    for (int j = 0; j < 4; j++){
      long gc = tC + wn*64 + j*16 + r16;
      f32x4 v = acc[i][j];
      ushort4 x0 = *(const ushort4*)(S0 + gc*2048 + gi);
      *(u32*)(Wq + gc*2048 + gi) = pack4_e4((2.f*v[0] - bf2f(x0.x))*256.f,
                                            (2.f*v[1] - bf2f(x0.y))*256.f,
                                            (2.f*v[2] - bf2f(x0.z))*256.f,
                                            (2.f*v[3] - bf2f(x0.w))*256.f);
    }
  }
}

// ---------- fp8 batched diffusion (gate): z selects {S0,V,R,W}; writes D slice z+1 ----------
template<int FP>
__global__ __launch_bounds__(256) void gemm_diff8(const u8* __restrict__ M0, const u8* __restrict__ M1,
                                                  const u8* __restrict__ M2, const u8* __restrict__ M3,
                                                  const u8* __restrict__ X, u16* __restrict__ D, long ldD){
  __shared__ u8 lA[16384];
  __shared__ u8 lB[16384];
  f32x4 acc[4][4];
  int z = blockIdx.z;
  const u8* A = (z == 0) ? M0 : (z == 1) ? M1 : (z == 2) ? M2 : M3;
  long tM = (long)blockIdx.x * 128, tC = (long)blockIdx.y * 128;
  gemm_core8(A, X, 2048, tM, tC, lA, lB, acc);

  int tid = threadIdx.x, wv = tid >> 6, lane = tid & 63;
  int q = lane >> 4, r16 = lane & 15, wm = wv & 1, wn = wv >> 1;
  int zb = (z + 1) * FP;
  #pragma unroll
  for (int i = 0; i < 4; i++){
    long gi = tM + wm*64 + i*16 + q*4;
    #pragma unroll
    for (int j = 0; j < 4; j++){
      int gc = (int)(tC + wn*64 + j*16 + r16);
      int b = gc / FP, f = gc - b*FP;
      long rb = (long)b*2048 + gi;
      f32x4 v = acc[i][j];
      D[(rb+0)*ldD + zb + f] = f2bf(v[0]);
      D[(rb+1)*ldD + zb + f] = f2bf(v[1]);
      D[(rb+2)*ldD + zb + f] = f2bf(v[2]);
      D[(rb+3)*ldD + zb + f] = f2bf(v[3]);
    }
  }
}

// ---------- fp8 candidate diffusion: Xr (2048 x 2048), writes D col (z+1)*Fp+fin+u ----------
__global__ __launch_bounds__(256) void gemm_diff8_c(const u8* __restrict__ M0, const u8* __restrict__ M1,
                                                    const u8* __restrict__ M2, const u8* __restrict__ M3,
                                                    const u8* __restrict__ Xr, u16* __restrict__ D,
                                                    long ldD, int Fp, int fin){
  __shared__ u8 lA[16384];
  __shared__ u8 lB[16384];
  f32x4 acc[4][4];
  int z = blockIdx.z;
  const u8* A = (z == 0) ? M0 : (z == 1) ? M1 : (z == 2) ? M2 : M3;
  long tM = (long)blockIdx.x * 128, tC = (long)blockIdx.y * 128;
  gemm_core8(A, Xr, 2048, tM, tC, lA, lB, acc);

  int tid = threadIdx.x, wv = tid >> 6, lane = tid & 63;
  int q = lane >> 4, r16 = lane & 15, wm = wv & 1, wn = wv >> 1;
  int zb = (z + 1) * Fp + fin;
  #pragma unroll
  for (int i = 0; i < 4; i++){
    long gi = tM + wm*64 + i*16 + q*4;
    #pragma unroll
    for (int j = 0; j < 4; j++){
      int gc = (int)(tC + wn*64 + j*16 + r16);
      int b = gc >> 6, u = gc & 63;
      long rb = (long)b*2048 + gi;
      f32x4 v = acc[i][j];
      D[(rb+0)*ldD + zb + u] = f2bf(v[0]);
      D[(rb+1)*ldD + zb + u] = f2bf(v[1]);
      D[(rb+2)*ldD + zb + u] = f2bf(v[2]);
      D[(rb+3)*ldD + zb + u] = f2bf(v[3]);
    }
  }
}

// ---------- dense (bf16): OutT[c][i] = sum_k A[i,k]*Bt[c,k] ----------
__global__ __launch_bounds__(256) void gemm_dense(const u16* __restrict__ A, const u16* __restrict__ Bt,
                                                  float* __restrict__ Out, int K, long ldOut){
  __shared__ u16 lA[8192];
  __shared__ u16 lB[8192];
  f32x4 acc[4][4];
  long tM = (long)blockIdx.x * 128, tC = (long)blockIdx.y * 128;
  gemm_core(A, Bt, K, tM, tC, lA, lB, acc);

  int tid = threadIdx.x, wv = tid >> 6, lane = tid & 63;
  int q = lane >> 4, r16 = lane & 15, wm = wv & 1, wn = wv >> 1;
  #pragma unroll
  for (int i = 0; i < 4; i++){
    long gi = tM + wm*64 + i*16 + q*4;
    #pragma unroll
    for (int j = 0; j < 4; j++){
      long gc = tC + wn*64 + j*16 + r16;
      *(f32x4*)(Out + gc*ldOut + gi) = acc[i][j];
    }
  }
}

// ---------- GRU epilogues ----------
// r = sigmoid(GT+bg); Xr8[(b*64+u)*2048+n] = e4m3(r*hx); D col (coloff+u) = bf16(r*hx)
__global__ __launch_bounds__(256) void k_gate_ep(const float* __restrict__ GT, const float* __restrict__ bg,
                                                 const float* __restrict__ hid, u8* __restrict__ Xr8,
                                                 u16* __restrict__ D, long ldD, int coloff){
  __shared__ float t[64*66];
  __shared__ u16 tb[64*66];
  int b = blockIdx.x, n0 = blockIdx.y * 64;
  int tid = threadIdx.x;
  long bn0 = (long)b*2048 + n0;
  for (int e = tid; e < 4096; e += 256){
    int u = e & 63, ni = e >> 6;            // lane->u: f32 hid read coalesced
    t[ni*66 + u] = hid[(bn0 + ni)*64 + u];
  }
  __syncthreads();
  for (int e = tid; e < 4096; e += 256){
    int u = e >> 6, ni = e & 63;            // lane->ni: GT read + Xr8 write coalesced
    float r = sigf(GT[(long)u*65536 + bn0 + ni] + bg[u]);
    float pv = r * t[ni*66 + u];
    Xr8[((long)b*64 + u)*2048 + n0 + ni] = f2e4(pv);
    tb[ni*66 + u] = f2bf(pv);
  }
  __syncthreads();
  for (int e = tid; e < 4096; e += 256){
    int ni = e >> 6, u = e & 63;            // lane->u: D col write coalesced
    D[(bn0 + ni)*ldD + coloff + u] = tb[ni*66 + u];
  }
}

__global__ __launch_bounds__(256) void k_cand_ep(const float* __restrict__ CT, const float* __restrict__ GT,
                                                 const float* __restrict__ bc, const float* __restrict__ bg,
                                                 const float* __restrict__ hx, float* __restrict__ hout,
                                                 u8* __restrict__ X0T_next, u16* __restrict__ Dnext,
                                                 const float* __restrict__ wproj, const float* __restrict__ bproj,
                                                 float* __restrict__ out){
  __shared__ u16 tc[64*66];
  __shared__ u16 tu[64*66];
  __shared__ u16 th[64*66];
  int b = blockIdx.x, n0 = blockIdx.y * 64;
  int tid = threadIdx.x;
  long bn0 = (long)b*2048 + n0;
  for (int e = tid; e < 4096; e += 256){
    int u = e >> 6, ni = e & 63;
    float cv = tanhf(CT[(long)u*65536 + bn0 + ni] + bc[u]);
    float uv = sigf(GT[(long)(64+u)*65536 + bn0 + ni] + bg[64+u]);
    tc[ni*66 + u] = f2bf(cv);
    tu[ni*66 + u] = f2bf(uv);
  }
  __syncthreads();
  int lane = tid & 63, wv = tid >> 6;
  for (int it = 0; it < 16; ++it){
    int ni = it*4 + wv, u = lane;
    float hxv = hx[(bn0 + ni)*64 + u];
    float uv = bf2f(tu[ni*66 + u]), cv = bf2f(tc[ni*66 + u]);
    float h = uv*hxv + (1.f - uv)*cv;
    hout[(bn0 + ni)*64 + u] = h;
    if (Dnext) Dnext[(bn0 + ni)*640 + u] = f2bf(h);
    th[ni*66 + u] = f2bf(h);
    if (wproj){
      float v = h * wproj[u];
      for (int off = 32; off; off >>= 1) v += __shfl_down(v, off, 64);
      if (lane == 0) out[(long)b*2048 + n0 + ni] = v + bproj[0];
    }
  }
  __syncthreads();
  if (X0T_next){
    for (int e = tid; e < 4096; e += 256){
      int u = e >> 6, ni = e & 63;          // lane->ni: fp8 row write coalesced
      X0T_next[((long)b*128 + u)*2048 + n0 + ni] = f2e4(bf2f(th[ni*66 + u]));
    }
  }
}

// ---------- launch ----------
extern "C" void kernel_launch(void* const* d_in, const int* in_sizes, int n_in,
                              void* d_out, int out_size, void* d_ws, size_t ws_size,
                              hipStream_t stream){
  (void)in_sizes; (void)n_in; (void)out_size; (void)ws_size;
  const float* inputs = (const float*)d_in[0];
  const float* hidden = (const float*)d_in[1];
  const float* adj    = (const float*)d_in[2];
  const float* wg0 = (const float*)d_in[3];
  const float* bg0 = (const float*)d_in[4];
  const float* wc0 = (const float*)d_in[5];
  const float* bc0 = (const float*)d_in[6];
  const float* wg1 = (const float*)d_in[7];
  const float* bg1 = (const float*)d_in[8];
  const float* wc1 = (const float*)d_in[9];
  const float* bc1 = (const float*)d_in[10];
  const float* wp  = (const float*)d_in[11];
  const float* bp  = (const float*)d_in[12];
  float* out = (float*)d_out;

  char* p = (char*)d_ws;
  auto alloc = [&](size_t bytes)->char*{ char* r = p; p += (bytes + 255) & ~(size_t)255; return r; };
  float* inv_rs = (float*)alloc(2048*4);
  float* inv_cs = (float*)alloc(2048*4);
  float* cs     = (float*)alloc(2048*4);
  const size_t SB  = (size_t)2048*2048*2;   // bf16 NxN
  const size_t SB8 = (size_t)2048*2048;     // fp8 NxN
  u16* S0  = (u16*)alloc(SB);
  u16* S0T = (u16*)alloc(SB);
  u16* S1  = (u16*)alloc(SB);
  u16* RT  = (u16*)alloc(SB);
  u8*  S0q = (u8*)alloc(SB8);
  u8*  Rq  = (u8*)alloc(SB8);
  u8*  Vq  = (u8*)alloc(SB8);
  u8*  Wq  = (u8*)alloc(SB8);
  u8*  X0a8 = (u8*)alloc((size_t)2304*2048); // layer0 cat, fp8, Fp=72
  u8*  X0b8 = (u8*)alloc((size_t)4096*2048); // layer1 cat, fp8, Fp=128
  u8*  Xr8  = (u8*)alloc(SB8);               // r*hx, fp8
  u16* D   = (u16*)alloc((size_t)65536*640*2);
  float* GT = (float*)alloc((size_t)128*65536*4);
  float* CT = (float*)alloc((size_t)128*65536*4);
  u16* WTg0 = (u16*)alloc((size_t)128*384*2);
  u16* WTc0 = (u16*)alloc((size_t)128*384*2);
  u16* WTg1 = (u16*)alloc((size_t)128*640*2);
  u16* WTc1 = (u16*)alloc((size_t)128*640*2);

  const float* hid0 = hidden;
  const float* hid1 = hidden + (size_t)4194304;
  float* h0out = out + 65536;
  float* h1out = out + 65536 + 4194304;

  // ---- setup ----
  k_rowsum<<<2048, 256, 0, stream>>>(adj, inv_rs);
  k_zero<<<8, 256, 0, stream>>>(cs);
  k_colsum2<<<dim3(32,16), 256, 0, stream>>>(adj, cs);
  k_inv<<<8, 256, 0, stream>>>(cs, inv_cs);
  k_build_S0 <<<dim3(32,32), 256, 0, stream>>>(adj, inv_rs, S0);
  k_build_S0T<<<4096, 256, 0, stream>>>(adj, inv_rs, S0T);
  k_build_S1 <<<4096, 256, 0, stream>>>(adj, inv_cs, S1);
  k_q8<<<2048, 256, 0, stream>>>(S0, S0q, 256.f);
  k_packW<<<192, 256, 0, stream>>>(wg0, WTg0, 128, 65, 72, 384);
  k_packW<<<192, 256, 0, stream>>>(wc0, WTc0,  64, 65, 72, 384);
  k_packW<<<320, 256, 0, stream>>>(wg1, WTg1, 128, 128, 128, 640);
  k_packW<<<320, 256, 0, stream>>>(wc1, WTc1,  64, 128, 128, 640);
  k_hx_build<<<dim3(32,32), 256, 0, stream>>>(hid0, inputs, X0a8, D, 72, 1, 384, 1, 1);

  // ---- precompute diffusion operators (bf16 compute, fp8 x256 output) ----
  gemm_pre<<<dim3(16,16,2), 256, 0, stream>>>(S0T, S1, S0, Rq, RT, Vq);
  gemm_w  <<<dim3(16,16),   256, 0, stream>>>(RT, S1, S0, Wq);

  dim3 gD0(16, 18, 4), gD1(16, 32, 4), gDc(16, 16, 4), gDen(512, 1), gE(32, 32);

  // ---- layer 0 gate ----
  gemm_diff8<72><<<gD0, 256, 0, stream>>>(S0q, Vq, Rq, Wq, X0a8, D, 384);
  gemm_dense<<<gDen, 256, 0, stream>>>(D, WTg0, GT, 384, 65536);
  k_gate_ep<<<gE, 256, 0, stream>>>(GT, bg0, hid0, Xr8, D, 384, 1);

  // ---- layer 0 candidate (diffuse only r*hx; inp cols reused from gate pass) ----
  gemm_diff8_c<<<gDc, 256, 0, stream>>>(S0q, Vq, Rq, Wq, Xr8, D, 384, 72, 1);
  gemm_dense<<<gDen, 256, 0, stream>>>(D, WTc0, CT, 384, 65536);
  k_cand_ep<<<gE, 256, 0, stream>>>(CT, GT, bc0, bg0, hid0, h0out, X0b8, D, nullptr, nullptr, nullptr);

  // ---- layer 1 build ----
  k_hx_build<<<dim3(32,32), 256, 0, stream>>>(hid1, nullptr, X0b8, D, 128, 64, 640, 64, 0);

  // ---- layer 1 gate ----
  gemm_diff8<128><<<gD1, 256, 0, stream>>>(S0q, Vq, Rq, Wq, X0b8, D, 640);
  gemm_dense<<<gDen, 256, 0, stream>>>(D, WTg1, GT, 640, 65536);
  k_gate_ep<<<gE, 256, 0, stream>>>(GT, bg1, hid1, Xr8, D, 640, 64);

  // ---- layer 1 candidate ----
  gemm_diff8_c<<<gDc, 256, 0, stream>>>(S0q, Vq, Rq, Wq, Xr8, D, 640, 128, 64);
  gemm_dense<<<gDen, 256, 0, stream>>>(D, WTc1, CT, 640, 65536);
  k_cand_ep<<<gE, 256, 0, stream>>>(CT, GT, bc1, bg1, hid1, h1out, nullptr, nullptr, wp, bp, out);
}

// Round 7
// 602.848 us; speedup vs baseline: 2.3763x; 1.0347x over previous
//
#include <hip/hip_runtime.h>

typedef unsigned short u16;
typedef unsigned char u8;
typedef unsigned int u32;
typedef float f32x4 __attribute__((ext_vector_type(4)));
typedef __bf16 bf16x8 __attribute__((ext_vector_type(8)));
typedef int i32x8 __attribute__((ext_vector_type(8)));

// MX scale bytes (E8M0: 2^(b-127)): A-side 2^-8 (S matrices quantized x256), B-side 1.0
#define SCL_A 0x77777777
#define SCL_B 0x7F7F7F7F

// ---------- helpers ----------
__device__ __forceinline__ u16 f2bf(float f){
  u32 u = __builtin_bit_cast(u32, f);
  u32 r = (u + 0x7fffu + ((u >> 16) & 1u)) >> 16;
  return (u16)r;
}
__device__ __forceinline__ float bf2f(u16 h){
  return __builtin_bit_cast(float, ((u32)h) << 16);
}
__device__ __forceinline__ u8 f2e4(float x){
  return (u8)(__builtin_amdgcn_cvt_pk_fp8_f32(x, x, 0, false) & 0xff);
}
__device__ __forceinline__ u32 pack4_e4(float a, float b, float c, float d){
  int w = __builtin_amdgcn_cvt_pk_fp8_f32(a, b, 0, false);
  w = __builtin_amdgcn_cvt_pk_fp8_f32(c, d, w, true);
  return (u32)w;
}
__device__ __forceinline__ void gl_lds16(const void* g, void* l){
  __builtin_amdgcn_global_load_lds((__attribute__((address_space(1))) void*)g,
                                   (__attribute__((address_space(3))) void*)l,
                                   16, 0, 0);
}
__device__ __forceinline__ float sigf(float x){ return 1.f/(1.f + __expf(-x)); }

// ---------- sums ----------
__global__ __launch_bounds__(256) void k_rowsum(const float* __restrict__ adj, float* __restrict__ inv_rs){
  int j = blockIdx.x; int tid = threadIdx.x;
  float s = 0.f;
  for (int i = tid; i < 2048; i += 256) s += adj[(long)j*2048 + i];
  for (int off = 32; off; off >>= 1) s += __shfl_down(s, off, 64);
  __shared__ float red[4];
  if ((tid & 63) == 0) red[tid >> 6] = s;
  __syncthreads();
  if (tid == 0){
    float t = red[0] + red[1] + red[2] + red[3];
    inv_rs[j] = 1.f / fmaxf(t, 1e-8f);
  }
}

__global__ __launch_bounds__(256) void k_zero(float* __restrict__ p){
  p[blockIdx.x*256 + threadIdx.x] = 0.f;
}

__global__ __launch_bounds__(256) void k_colsum2(const float* __restrict__ adj, float* __restrict__ cs){
  int j0 = blockIdx.x * 64, i0 = blockIdx.y * 128;
  int jj = threadIdx.x & 63, w = threadIdx.x >> 6;
  float s = 0.f;
  for (int i = w; i < 128; i += 4) s += adj[(long)(i0+i)*2048 + j0 + jj];
  __shared__ float red[256];
  red[threadIdx.x] = s;
  __syncthreads();
  if (w == 0){
    float t = red[jj] + red[64+jj] + red[128+jj] + red[192+jj];
    atomicAdd(&cs[j0+jj], t);
  }
}

__global__ __launch_bounds__(256) void k_inv(const float* __restrict__ cs, float* __restrict__ inv_cs){
  int i = blockIdx.x*256 + threadIdx.x;
  inv_cs[i] = 1.f / fmaxf(cs[i], 1e-8f);
}

// S0[i][j] = adj[j][i] * inv_rs[j]  (LDS-tiled transpose)
__global__ __launch_bounds__(256) void k_build_S0(const float* __restrict__ adj, const float* __restrict__ inv_rs, u16* __restrict__ S0){
  __shared__ u16 t[64*66];
  int i0 = blockIdx.x * 64, j0 = blockIdx.y * 64;
  int tid = threadIdx.x;
  for (int e = tid; e < 4096; e += 256){
    int jj = e >> 6, ii = e & 63;
    t[jj*66 + ii] = f2bf(adj[(long)(j0+jj)*2048 + i0 + ii] * inv_rs[j0+jj]);
  }
  __syncthreads();
  for (int e = tid; e < 4096; e += 256){
    int ii = e >> 6, jj = e & 63;
    S0[(long)(i0+ii)*2048 + j0 + jj] = t[jj*66 + ii];
  }
}

// S0T[j][i] = adj[j][i] * inv_rs[j]
__global__ __launch_bounds__(256) void k_build_S0T(const float* __restrict__ adj, const float* __restrict__ inv_rs, u16* __restrict__ S0T){
  long idx = ((long)blockIdx.x*256 + threadIdx.x) * 4;
  int j = (int)(idx >> 11);
  float s = inv_rs[j];
  float4 a = *(const float4*)(adj + idx);
  ushort4 o;
  o.x = f2bf(a.x * s); o.y = f2bf(a.y * s);
  o.z = f2bf(a.z * s); o.w = f2bf(a.w * s);
  *(ushort4*)(S0T + idx) = o;
}

// S1[i][j] = adj[i][j] * inv_cs[j]
__global__ __launch_bounds__(256) void k_build_S1(const float* __restrict__ adj, const float* __restrict__ inv_cs, u16* __restrict__ S1){
  long idx = ((long)blockIdx.x*256 + threadIdx.x) * 4;
  int j = (int)(idx & 2047);
  float4 a = *(const float4*)(adj + idx);
  float4 c = *(const float4*)(inv_cs + j);
  ushort4 o;
  o.x = f2bf(a.x * c.x); o.y = f2bf(a.y * c.y);
  o.z = f2bf(a.z * c.z); o.w = f2bf(a.w * c.w);
  *(ushort4*)(S1 + idx) = o;
}

// bf16 -> e4m3 with scale (8 elems/thread)
__global__ __launch_bounds__(256) void k_q8(const u16* __restrict__ src, u8* __restrict__ dst, float scale){
  long i = ((long)blockIdx.x*256 + threadIdx.x) * 8;
  ushort4 s0 = *(const ushort4*)(src + i);
  ushort4 s1 = *(const ushort4*)(src + i + 4);
  u32 w0 = pack4_e4(bf2f(s0.x)*scale, bf2f(s0.y)*scale, bf2f(s0.z)*scale, bf2f(s0.w)*scale);
  u32 w1 = pack4_e4(bf2f(s1.x)*scale, bf2f(s1.y)*scale, bf2f(s1.z)*scale, bf2f(s1.w)*scale);
  uint2 o; o.x = w0; o.y = w1;
  *(uint2*)(dst + i) = o;
}

// WT[o][k] = w[(f*5+m)*OUTr + o] for k=(m,f), zero-padded.  WT is 128 x Kd.
__global__ __launch_bounds__(256) void k_packW(const float* __restrict__ w, u16* __restrict__ WT,
                                               int OUTr, int F, int Fp, int Kd){
  int idx = blockIdx.x*256 + threadIdx.x;
  if (idx >= 128*Kd) return;
  int o = idx / Kd, k = idx - o*Kd;
  int m = k / Fp, f = k - m*Fp;
  float v = 0.f;
  if (o < OUTr && m < 5 && f < F) v = w[(long)(f*5 + m)*OUTr + o];
  WT[idx] = f2bf(v);
}

// hidden (f32) -> fp8 X0T rows (b, rowoff+u) + bf16 D cols (coloff+u); layer-0 extras: inp + pads
__global__ __launch_bounds__(256) void k_hx_build(const float* __restrict__ hx, const float* __restrict__ inp,
                                                  u8* __restrict__ X0T, u16* __restrict__ D,
                                                  int Fp, int rowoff, long ldD, int coloff, int l0extras){
  __shared__ float t[64*66];
  int b = blockIdx.x, n0 = blockIdx.y * 64;
  int tid = threadIdx.x;
  const float* hb = hx + (long)b*2048*64;
  long bn0 = (long)b*2048 + n0;
  for (int e = tid; e < 4096; e += 256){
    int u = e & 63, ni = e >> 6;            // lane->u: f32 read coalesced
    t[ni*66 + u] = hb[(long)(n0+ni)*64 + u];
  }
  __syncthreads();
  for (int e = tid; e < 4096; e += 256){
    int u = e >> 6, ni = e & 63;            // lane->ni: fp8 row write coalesced
    X0T[((long)b*Fp + rowoff + u)*2048 + n0 + ni] = f2e4(t[ni*66 + u]);
  }
  for (int e = tid; e < 4096; e += 256){
    int ni = e >> 6, u = e & 63;            // lane->u: D col write coalesced
    D[(bn0 + ni)*ldD + coloff + u] = f2bf(t[ni*66 + u]);
  }
  if (l0extras){
    if (tid < 64){
      float v = inp[(long)b*2048 + n0 + tid];
      X0T[((long)b*Fp)*2048 + n0 + tid] = f2e4(v);
      D[(bn0 + tid)*ldD] = f2bf(v);
    }
    for (int e = tid; e < 7*64; e += 256){
      int f = 65 + (e >> 6), ni = e & 63;
      X0T[((long)b*Fp + f)*2048 + n0 + ni] = 0;
    }
    for (int e = tid; e < 64*31; e += 256){
      int ni = e / 31, wc = e - ni*31;
      int col = (wc < 7) ? (65 + wc) : (353 + wc);   // {65..71, 360..383}
      D[(bn0 + ni)*ldD + col] = 0;
    }
  }
}

// ---------- bf16 GEMM core, BK=64 (precompute + dense) ----------
__device__ __forceinline__ void gemm_core(const u16* __restrict__ A, const u16* __restrict__ Bt,
                                          int K, long tM, long tC,
                                          u16* lA, u16* lB, f32x4 (&acc)[4][4]){
  int tid = threadIdx.x;
  int wv = tid >> 6, lane = tid & 63;
  int q = lane >> 4, r16 = lane & 15;

  const u16* ga[4]; const u16* gb[4];
  u16* la[4]; u16* lb[4];
  #pragma unroll
  for (int it = 0; it < 4; it++){
    int L = it*256 + tid;
    int r = L >> 3, g = (L & 7) ^ (r & 7);
    ga[it] = A  + (tM + r)*(long)K + g*8;
    gb[it] = Bt + (tC + r)*(long)K + g*8;
    la[it] = lA + (it*256 + wv*64)*8;
    lb[it] = lB + (it*256 + wv*64)*8;
  }

  #pragma unroll
  for (int i = 0; i < 4; i++)
    #pragma unroll
    for (int j = 0; j < 4; j++){ acc[i][j][0]=0.f; acc[i][j][1]=0.f; acc[i][j][2]=0.f; acc[i][j][3]=0.f; }

  int wm = wv & 1, wn = wv >> 1;
  int aoff[4][2], boff[4][2];
  #pragma unroll
  for (int s = 0; s < 4; s++){
    int m = wm*64 + s*16 + r16;
    int n = wn*64 + s*16 + r16;
    #pragma unroll
    for (int h = 0; h < 2; h++){
      aoff[s][h] = (m*8 + ((h*4 + q) ^ (m & 7))) * 8;
      boff[s][h] = (n*8 + ((h*4 + q) ^ (n & 7))) * 8;
    }
  }

  for (int k0 = 0; k0 < K; k0 += 64){
    __syncthreads();
    #pragma unroll
    for (int it = 0; it < 4; it++){
      gl_lds16(ga[it] + k0, la[it]);
      gl_lds16(gb[it] + k0, lb[it]);
    }
    asm volatile("s_waitcnt vmcnt(0)" ::: "memory");
    __syncthreads();
    #pragma unroll
    for (int h = 0; h < 2; h++){
      bf16x8 af[4], bfr[4];
      #pragma unroll
      for (int s = 0; s < 4; s++){
        af[s]  = *(const bf16x8*)&lA[aoff[s][h]];
        bfr[s] = *(const bf16x8*)&lB[boff[s][h]];
      }
      #pragma unroll
      for (int i = 0; i < 4; i++)
        #pragma unroll
        for (int j = 0; j < 4; j++)
          acc[i][j] = __builtin_amdgcn_mfma_f32_16x16x32_bf16(af[i], bfr[j], acc[i][j], 0, 0, 0);
    }
  }
}

// ---------- fp8 MX GEMM core, BK=128 bytes ----------
// Storage permutation sigma(g) = (g>>1)|((g&1)<<2) so the frag-read slot
// pattern is (e*4+q)^(m&7) -- byte-identical to the bf16 core's pattern,
// which measured SQ_LDS_BANK_CONFLICT = 0 (R5) vs 4 cyc/read for the
// (2q+e)^(m&7) pattern (R6). Slot s of row r holds global chunk
// g = sigma^-1(s^(r&7)), staged via the linear-lane global_load_lds rule.
// Frag read slot (e*4+q)^(m&7) yields g = sigma^-1(e*4+q) = 2q+e. ✓
__device__ __forceinline__ void gemm_core8(const u8* __restrict__ A, const u8* __restrict__ Bt,
                                           int K, long tM, long tC,
                                           u8* lA, u8* lB, f32x4 (&acc)[4][4]){
  int tid = threadIdx.x;
  int wv = tid >> 6, lane = tid & 63;
  int q = lane >> 4, r16 = lane & 15;

  const u8* ga[4]; const u8* gb[4];
  u8* la[4]; u8* lb[4];
  #pragma unroll
  for (int it = 0; it < 4; it++){
    int L = it*256 + tid;
    int r = L >> 3, x = (L & 7) ^ (r & 7);
    int g = ((x & 3) << 1) | (x >> 2);     // sigma^-1
    ga[it] = A  + (tM + r)*(long)K + g*16;
    gb[it] = Bt + (tC + r)*(long)K + g*16;
    la[it] = lA + (it*256 + wv*64)*16;
    lb[it] = lB + (it*256 + wv*64)*16;
  }

  #pragma unroll
  for (int i = 0; i < 4; i++)
    #pragma unroll
    for (int j = 0; j < 4; j++){ acc[i][j][0]=0.f; acc[i][j][1]=0.f; acc[i][j][2]=0.f; acc[i][j][3]=0.f; }

  int wm = wv & 1, wn = wv >> 1;
  int aoff[4][2], boff[4][2];
  #pragma unroll
  for (int s = 0; s < 4; s++){
    int m = wm*64 + s*16 + r16;
    int n = wn*64 + s*16 + r16;
    #pragma unroll
    for (int e = 0; e < 2; e++){
      aoff[s][e] = m*128 + ((e*4 + q) ^ (m & 7)) * 16;
      boff[s][e] = n*128 + ((e*4 + q) ^ (n & 7)) * 16;
    }
  }

  for (int k0 = 0; k0 < K; k0 += 128){
    __syncthreads();
    #pragma unroll
    for (int it = 0; it < 4; it++){
      gl_lds16(ga[it] + k0, la[it]);
      gl_lds16(gb[it] + k0, lb[it]);
    }
    asm volatile("s_waitcnt vmcnt(0)" ::: "memory");
    __syncthreads();
    i32x8 af[4], bfr[4];
    #pragma unroll
    for (int s = 0; s < 4; s++){
      uint4 a0 = *(const uint4*)&lA[aoff[s][0]];
      uint4 a1 = *(const uint4*)&lA[aoff[s][1]];
      i32x8 av; av[0]=a0.x; av[1]=a0.y; av[2]=a0.z; av[3]=a0.w; av[4]=a1.x; av[5]=a1.y; av[6]=a1.z; av[7]=a1.w;
      af[s] = av;
      uint4 b0 = *(const uint4*)&lB[boff[s][0]];
      uint4 b1 = *(const uint4*)&lB[boff[s][1]];
      i32x8 bv; bv[0]=b0.x; bv[1]=b0.y; bv[2]=b0.z; bv[3]=b0.w; bv[4]=b1.x; bv[5]=b1.y; bv[6]=b1.z; bv[7]=b1.w;
      bfr[s] = bv;
    }
    #pragma unroll
    for (int i = 0; i < 4; i++)
      #pragma unroll
      for (int j = 0; j < 4; j++)
        acc[i][j] = __builtin_amdgcn_mfma_scale_f32_16x16x128_f8f6f4(
                      af[i], bfr[j], acc[i][j], 0, 0, 0, SCL_A, 0, SCL_B);
  }
}

// ---------- precompute: z=0: R=S1@S0 -> RT(bf16) + Rq(e4m3 x256); z=1: V=2*S0^2-I -> Vq ----------
__global__ __launch_bounds__(256) void gemm_pre(const u16* __restrict__ S0T, const u16* __restrict__ S1,
                                                const u16* __restrict__ S0,
                                                u8* __restrict__ Rq, u16* __restrict__ RT, u8* __restrict__ Vq){
  __shared__ u16 lA[8192];
  __shared__ u16 lB[8192];
  f32x4 acc[4][4];
  const u16* Bt = (blockIdx.z == 0) ? S1 : S0;
  long tM = (long)blockIdx.x * 128, tC = (long)blockIdx.y * 128;
  gemm_core(S0T, Bt, 2048, tM, tC, lA, lB, acc);

  int tid = threadIdx.x, wv = tid >> 6, lane = tid & 63;
  int q = lane >> 4, r16 = lane & 15, wm = wv & 1, wn = wv >> 1;
  #pragma unroll
  for (int i = 0; i < 4; i++){
    long gi = tM + wm*64 + i*16 + q*4;
    #pragma unroll
    for (int j = 0; j < 4; j++){
      long gc = tC + wn*64 + j*16 + r16;
      f32x4 v = acc[i][j];
      if (blockIdx.z == 0){
        *(u32*)(Rq + gc*2048 + gi) = pack4_e4(v[0]*256.f, v[1]*256.f, v[2]*256.f, v[3]*256.f);
        RT[(gi+0)*2048 + gc] = f2bf(v[0]);
        RT[(gi+1)*2048 + gc] = f2bf(v[1]);
        RT[(gi+2)*2048 + gc] = f2bf(v[2]);
        RT[(gi+3)*2048 + gc] = f2bf(v[3]);
      } else {
        float x0 = 2.f*v[0] - ((gi+0) == gc ? 1.f : 0.f);
        float x1 = 2.f*v[1] - ((gi+1) == gc ? 1.f : 0.f);
        float x2 = 2.f*v[2] - ((gi+2) == gc ? 1.f : 0.f);
        float x3 = 2.f*v[3] - ((gi+3) == gc ? 1.f : 0.f);
        *(u32*)(Vq + gc*2048 + gi) = pack4_e4(x0*256.f, x1*256.f, x2*256.f, x3*256.f);
      }
    }
  }
}

// ---------- precompute: W = 2*S1@R - S0 -> Wq(e4m3 x256) ----------
__global__ __launch_bounds__(256) void gemm_w(const u16* __restrict__ RT, const u16* __restrict__ S1,
                                              const u16* __restrict__ S0, u8* __restrict__ Wq){
  __shared__ u16 lA[8192];
  __shared__ u16 lB[8192];
  f32x4 acc[4][4];
  long tM = (long)blockIdx.x * 128, tC = (long)blockIdx.y * 128;
  gemm_core(RT, S1, 2048, tM, tC, lA, lB, acc);

  int tid = threadIdx.x, wv = tid >> 6, lane = tid & 63;
  int q = lane >> 4, r16 = lane & 15, wm = wv & 1, wn = wv >> 1;
  #pragma unroll
  for (int i = 0; i < 4; i++){
    long gi = tM + wm*64 + i*16 + q*4;
    #pragma unroll
    for (int j = 0; j < 4; j++){
      long gc = tC + wn*64 + j*16 + r16;
      f32x4 v = acc[i][j];
      ushort4 x0 = *(const ushort4*)(S0 + gc*2048 + gi);
      *(u32*)(Wq + gc*2048 + gi) = pack4_e4((2.f*v[0] - bf2f(x0.x))*256.f,
                                            (2.f*v[1] - bf2f(x0.y))*256.f,
                                            (2.f*v[2] - bf2f(x0.z))*256.f,
                                            (2.f*v[3] - bf2f(x0.w))*256.f);
    }
  }
}

// ---------- fp8 batched diffusion (gate): z selects {S0,V,R,W}; writes D slice z+1 ----------
template<int FP>
__global__ __launch_bounds__(256) void gemm_diff8(const u8* __restrict__ M0, const u8* __restrict__ M1,
                                                  const u8* __restrict__ M2, const u8* __restrict__ M3,
                                                  const u8* __restrict__ X, u16* __restrict__ D, long ldD){
  __shared__ u8 lA[16384];
  __shared__ u8 lB[16384];
  f32x4 acc[4][4];
  int z = blockIdx.z;
  const u8* A = (z == 0) ? M0 : (z == 1) ? M1 : (z == 2) ? M2 : M3;
  long tM = (long)blockIdx.x * 128, tC = (long)blockIdx.y * 128;
  gemm_core8(A, X, 2048, tM, tC, lA, lB, acc);

  int tid = threadIdx.x, wv = tid >> 6, lane = tid & 63;
  int q = lane >> 4, r16 = lane & 15, wm = wv & 1, wn = wv >> 1;
  int zb = (z + 1) * FP;
  #pragma unroll
  for (int i = 0; i < 4; i++){
    long gi = tM + wm*64 + i*16 + q*4;
    #pragma unroll
    for (int j = 0; j < 4; j++){
      int gc = (int)(tC + wn*64 + j*16 + r16);
      int b = gc / FP, f = gc - b*FP;
      long rb = (long)b*2048 + gi;
      f32x4 v = acc[i][j];
      D[(rb+0)*ldD + zb + f] = f2bf(v[0]);
      D[(rb+1)*ldD + zb + f] = f2bf(v[1]);
      D[(rb+2)*ldD + zb + f] = f2bf(v[2]);
      D[(rb+3)*ldD + zb + f] = f2bf(v[3]);
    }
  }
}

// ---------- fp8 candidate diffusion: Xr (2048 x 2048), writes D col (z+1)*Fp+fin+u ----------
__global__ __launch_bounds__(256) void gemm_diff8_c(const u8* __restrict__ M0, const u8* __restrict__ M1,
                                                    const u8* __restrict__ M2, const u8* __restrict__ M3,
                                                    const u8* __restrict__ Xr, u16* __restrict__ D,
                                                    long ldD, int Fp, int fin){
  __shared__ u8 lA[16384];
  __shared__ u8 lB[16384];
  f32x4 acc[4][4];
  int z = blockIdx.z;
  const u8* A = (z == 0) ? M0 : (z == 1) ? M1 : (z == 2) ? M2 : M3;
  long tM = (long)blockIdx.x * 128, tC = (long)blockIdx.y * 128;
  gemm_core8(A, Xr, 2048, tM, tC, lA, lB, acc);

  int tid = threadIdx.x, wv = tid >> 6, lane = tid & 63;
  int q = lane >> 4, r16 = lane & 15, wm = wv & 1, wn = wv >> 1;
  int zb = (z + 1) * Fp + fin;
  #pragma unroll
  for (int i = 0; i < 4; i++){
    long gi = tM + wm*64 + i*16 + q*4;
    #pragma unroll
    for (int j = 0; j < 4; j++){
      int gc = (int)(tC + wn*64 + j*16 + r16);
      int b = gc >> 6, u = gc & 63;
      long rb = (long)b*2048 + gi;
      f32x4 v = acc[i][j];
      D[(rb+0)*ldD + zb + u] = f2bf(v[0]);
      D[(rb+1)*ldD + zb + u] = f2bf(v[1]);
      D[(rb+2)*ldD + zb + u] = f2bf(v[2]);
      D[(rb+3)*ldD + zb + u] = f2bf(v[3]);
    }
  }
}

// ---------- dense (bf16): OutT[c][i] = sum_k A[i,k]*Bt[c,k] ----------
__global__ __launch_bounds__(256) void gemm_dense(const u16* __restrict__ A, const u16* __restrict__ Bt,
                                                  float* __restrict__ Out, int K, long ldOut){
  __shared__ u16 lA[8192];
  __shared__ u16 lB[8192];
  f32x4 acc[4][4];
  long tM = (long)blockIdx.x * 128, tC = (long)blockIdx.y * 128;
  gemm_core(A, Bt, K, tM, tC, lA, lB, acc);

  int tid = threadIdx.x, wv = tid >> 6, lane = tid & 63;
  int q = lane >> 4, r16 = lane & 15, wm = wv & 1, wn = wv >> 1;
  #pragma unroll
  for (int i = 0; i < 4; i++){
    long gi = tM + wm*64 + i*16 + q*4;
    #pragma unroll
    for (int j = 0; j < 4; j++){
      long gc = tC + wn*64 + j*16 + r16;
      *(f32x4*)(Out + gc*ldOut + gi) = acc[i][j];
    }
  }
}

// ---------- GRU epilogues ----------
// r = sigmoid(GT+bg); Xr8[(b*64+u)*2048+n] = e4m3(r*hx); D col (coloff+u) = bf16(r*hx)
__global__ __launch_bounds__(256) void k_gate_ep(const float* __restrict__ GT, const float* __restrict__ bg,
                                                 const float* __restrict__ hid, u8* __restrict__ Xr8,
                                                 u16* __restrict__ D, long ldD, int coloff){
  __shared__ float t[64*66];
  __shared__ u16 tb[64*66];
  int b = blockIdx.x, n0 = blockIdx.y * 64;
  int tid = threadIdx.x;
  long bn0 = (long)b*2048 + n0;
  for (int e = tid; e < 4096; e += 256){
    int u = e & 63, ni = e >> 6;            // lane->u: f32 hid read coalesced
    t[ni*66 + u] = hid[(bn0 + ni)*64 + u];
  }
  __syncthreads();
  for (int e = tid; e < 4096; e += 256){
    int u = e >> 6, ni = e & 63;            // lane->ni: GT read + Xr8 write coalesced
    float r = sigf(GT[(long)u*65536 + bn0 + ni] + bg[u]);
    float pv = r * t[ni*66 + u];
    Xr8[((long)b*64 + u)*2048 + n0 + ni] = f2e4(pv);
    tb[ni*66 + u] = f2bf(pv);
  }
  __syncthreads();
  for (int e = tid; e < 4096; e += 256){
    int ni = e >> 6, u = e & 63;            // lane->u: D col write coalesced
    D[(bn0 + ni)*ldD + coloff + u] = tb[ni*66 + u];
  }
}

__global__ __launch_bounds__(256) void k_cand_ep(const float* __restrict__ CT, const float* __restrict__ GT,
                                                 const float* __restrict__ bc, const float* __restrict__ bg,
                                                 const float* __restrict__ hx, float* __restrict__ hout,
                                                 u8* __restrict__ X0T_next, u16* __restrict__ Dnext,
                                                 const float* __restrict__ wproj, const float* __restrict__ bproj,
                                                 float* __restrict__ out){
  __shared__ u16 tc[64*66];
  __shared__ u16 tu[64*66];
  __shared__ u16 th[64*66];
  int b = blockIdx.x, n0 = blockIdx.y * 64;
  int tid = threadIdx.x;
  long bn0 = (long)b*2048 + n0;
  for (int e = tid; e < 4096; e += 256){
    int u = e >> 6, ni = e & 63;
    float cv = tanhf(CT[(long)u*65536 + bn0 + ni] + bc[u]);
    float uv = sigf(GT[(long)(64+u)*65536 + bn0 + ni] + bg[64+u]);
    tc[ni*66 + u] = f2bf(cv);
    tu[ni*66 + u] = f2bf(uv);
  }
  __syncthreads();
  int lane = tid & 63, wv = tid >> 6;
  for (int it = 0; it < 16; ++it){
    int ni = it*4 + wv, u = lane;
    float hxv = hx[(bn0 + ni)*64 + u];
    float uv = bf2f(tu[ni*66 + u]), cv = bf2f(tc[ni*66 + u]);
    float h = uv*hxv + (1.f - uv)*cv;
    hout[(bn0 + ni)*64 + u] = h;
    if (Dnext) Dnext[(bn0 + ni)*640 + u] = f2bf(h);
    th[ni*66 + u] = f2bf(h);
    if (wproj){
      float v = h * wproj[u];
      for (int off = 32; off; off >>= 1) v += __shfl_down(v, off, 64);
      if (lane == 0) out[(long)b*2048 + n0 + ni] = v + bproj[0];
    }
  }
  __syncthreads();
  if (X0T_next){
    for (int e = tid; e < 4096; e += 256){
      int u = e >> 6, ni = e & 63;          // lane->ni: fp8 row write coalesced
      X0T_next[((long)b*128 + u)*2048 + n0 + ni] = f2e4(bf2f(th[ni*66 + u]));
    }
  }
}

// ---------- launch ----------
extern "C" void kernel_launch(void* const* d_in, const int* in_sizes, int n_in,
                              void* d_out, int out_size, void* d_ws, size_t ws_size,
                              hipStream_t stream){
  (void)in_sizes; (void)n_in; (void)out_size; (void)ws_size;
  const float* inputs = (const float*)d_in[0];
  const float* hidden = (const float*)d_in[1];
  const float* adj    = (const float*)d_in[2];
  const float* wg0 = (const float*)d_in[3];
  const float* bg0 = (const float*)d_in[4];
  const float* wc0 = (const float*)d_in[5];
  const float* bc0 = (const float*)d_in[6];
  const float* wg1 = (const float*)d_in[7];
  const float* bg1 = (const float*)d_in[8];
  const float* wc1 = (const float*)d_in[9];
  const float* bc1 = (const float*)d_in[10];
  const float* wp  = (const float*)d_in[11];
  const float* bp  = (const float*)d_in[12];
  float* out = (float*)d_out;

  char* p = (char*)d_ws;
  auto alloc = [&](size_t bytes)->char*{ char* r = p; p += (bytes + 255) & ~(size_t)255; return r; };
  float* inv_rs = (float*)alloc(2048*4);
  float* inv_cs = (float*)alloc(2048*4);
  float* cs     = (float*)alloc(2048*4);
  const size_t SB  = (size_t)2048*2048*2;   // bf16 NxN
  const size_t SB8 = (size_t)2048*2048;     // fp8 NxN
  u16* S0  = (u16*)alloc(SB);
  u16* S0T = (u16*)alloc(SB);
  u16* S1  = (u16*)alloc(SB);
  u16* RT  = (u16*)alloc(SB);
  u8*  S0q = (u8*)alloc(SB8);
  u8*  Rq  = (u8*)alloc(SB8);
  u8*  Vq  = (u8*)alloc(SB8);
  u8*  Wq  = (u8*)alloc(SB8);
  u8*  X0a8 = (u8*)alloc((size_t)2304*2048); // layer0 cat, fp8, Fp=72
  u8*  X0b8 = (u8*)alloc((size_t)4096*2048); // layer1 cat, fp8, Fp=128
  u8*  Xr8  = (u8*)alloc(SB8);               // r*hx, fp8
  u16* D   = (u16*)alloc((size_t)65536*640*2);
  float* GT = (float*)alloc((size_t)128*65536*4);
  float* CT = (float*)alloc((size_t)128*65536*4);
  u16* WTg0 = (u16*)alloc((size_t)128*384*2);
  u16* WTc0 = (u16*)alloc((size_t)128*384*2);
  u16* WTg1 = (u16*)alloc((size_t)128*640*2);
  u16* WTc1 = (u16*)alloc((size_t)128*640*2);

  const float* hid0 = hidden;
  const float* hid1 = hidden + (size_t)4194304;
  float* h0out = out + 65536;
  float* h1out = out + 65536 + 4194304;

  // ---- setup ----
  k_rowsum<<<2048, 256, 0, stream>>>(adj, inv_rs);
  k_zero<<<8, 256, 0, stream>>>(cs);
  k_colsum2<<<dim3(32,16), 256, 0, stream>>>(adj, cs);
  k_inv<<<8, 256, 0, stream>>>(cs, inv_cs);
  k_build_S0 <<<dim3(32,32), 256, 0, stream>>>(adj, inv_rs, S0);
  k_build_S0T<<<4096, 256, 0, stream>>>(adj, inv_rs, S0T);
  k_build_S1 <<<4096, 256, 0, stream>>>(adj, inv_cs, S1);
  k_q8<<<2048, 256, 0, stream>>>(S0, S0q, 256.f);
  k_packW<<<192, 256, 0, stream>>>(wg0, WTg0, 128, 65, 72, 384);
  k_packW<<<192, 256, 0, stream>>>(wc0, WTc0,  64, 65, 72, 384);
  k_packW<<<320, 256, 0, stream>>>(wg1, WTg1, 128, 128, 128, 640);
  k_packW<<<320, 256, 0, stream>>>(wc1, WTc1,  64, 128, 128, 640);
  k_hx_build<<<dim3(32,32), 256, 0, stream>>>(hid0, inputs, X0a8, D, 72, 1, 384, 1, 1);

  // ---- precompute diffusion operators (bf16 compute, fp8 x256 output) ----
  gemm_pre<<<dim3(16,16,2), 256, 0, stream>>>(S0T, S1, S0, Rq, RT, Vq);
  gemm_w  <<<dim3(16,16),   256, 0, stream>>>(RT, S1, S0, Wq);

  dim3 gD0(16, 18, 4), gD1(16, 32, 4), gDc(16, 16, 4), gDen(512, 1), gE(32, 32);

  // ---- layer 0 gate ----
  gemm_diff8<72><<<gD0, 256, 0, stream>>>(S0q, Vq, Rq, Wq, X0a8, D, 384);
  gemm_dense<<<gDen, 256, 0, stream>>>(D, WTg0, GT, 384, 65536);
  k_gate_ep<<<gE, 256, 0, stream>>>(GT, bg0, hid0, Xr8, D, 384, 1);

  // ---- layer 0 candidate (diffuse only r*hx; inp cols reused from gate pass) ----
  gemm_diff8_c<<<gDc, 256, 0, stream>>>(S0q, Vq, Rq, Wq, Xr8, D, 384, 72, 1);
  gemm_dense<<<gDen, 256, 0, stream>>>(D, WTc0, CT, 384, 65536);
  k_cand_ep<<<gE, 256, 0, stream>>>(CT, GT, bc0, bg0, hid0, h0out, X0b8, D, nullptr, nullptr, nullptr);

  // ---- layer 1 build ----
  k_hx_build<<<dim3(32,32), 256, 0, stream>>>(hid1, nullptr, X0b8, D, 128, 64, 640, 64, 0);

  // ---- layer 1 gate ----
  gemm_diff8<128><<<gD1, 256, 0, stream>>>(S0q, Vq, Rq, Wq, X0b8, D, 640);
  gemm_dense<<<gDen, 256, 0, stream>>>(D, WTg1, GT, 640, 65536);
  k_gate_ep<<<gE, 256, 0, stream>>>(GT, bg1, hid1, Xr8, D, 640, 64);

  // ---- layer 1 candidate ----
  gemm_diff8_c<<<gDc, 256, 0, stream>>>(S0q, Vq, Rq, Wq, Xr8, D, 640, 128, 64);
  gemm_dense<<<gDen, 256, 0, stream>>>(D, WTc1, CT, 640, 65536);
  k_cand_ep<<<gE, 256, 0, stream>>>(CT, GT, bc1, bg1, hid1, h1out, nullptr, nullptr, wp, bp, out);
}